// Round 3
// baseline (3463.231 us; speedup 1.0000x reference)
//
#include <hip/hip_runtime.h>
#include <cmath>

typedef unsigned short u16;
typedef unsigned int   u32;
typedef short bhalf8 __attribute__((ext_vector_type(8)));
typedef float fx4    __attribute__((ext_vector_type(4)));

#define B_   4
#define S_   1024
#define D_   1024
#define H_   16
#define HD_  64
#define FF_  4096
#define NTOK (B_*S_)

__device__ __forceinline__ float b2f(u16 u) {
    u32 x = ((u32)u) << 16;
    return __uint_as_float(x);
}
__device__ __forceinline__ u16 f2b(float f) {
    u32 u = __float_as_uint(f);
    u32 r = (u + 0x7fffu + ((u >> 16) & 1u)) >> 16;
    return (u16)r;
}

// ---------------------------------------------------------------------------
// Convert the 8 GEMM weight matrices f32 -> bf16 into one contiguous ws block.
// Element layout: wq[1M] wk[1M] wv[1M] wo[1M] W1[4M] J1[4M] W2[4M] J2[4M].
// 8 elems/thread; segment boundaries are 1M-elem aligned so blocks never split.
// ---------------------------------------------------------------------------
__global__ __launch_bounds__(256) void cvt_k(const float* __restrict__ w0, const float* __restrict__ w1,
                                             const float* __restrict__ w2, const float* __restrict__ w3,
                                             const float* __restrict__ W1p, const float* __restrict__ J1p,
                                             const float* __restrict__ W2p, const float* __restrict__ J2p,
                                             u16* __restrict__ dst) {
    size_t idx = ((size_t)blockIdx.x * 256 + threadIdx.x) * 8;
    int seg = (int)(idx >> 20);
    const float* src;
    size_t off;
    if (seg < 4)       { src = seg == 0 ? w0 : seg == 1 ? w1 : seg == 2 ? w2 : w3; off = idx & ((1u << 20) - 1); }
    else if (seg < 8)  { src = W1p; off = idx - ((size_t)4 << 20); }
    else if (seg < 12) { src = J1p; off = idx - ((size_t)8 << 20); }
    else if (seg < 16) { src = W2p; off = idx - ((size_t)12 << 20); }
    else               { src = J2p; off = idx - ((size_t)16 << 20); }
    float4 a = *(const float4*)(src + off);
    float4 b = *(const float4*)(src + off + 4);
    u16 r[8] = {f2b(a.x), f2b(a.y), f2b(a.z), f2b(a.w), f2b(b.x), f2b(b.y), f2b(b.z), f2b(b.w)};
    *(uint4*)(dst + idx) = *(uint4*)r;
}

// ---------------------------------------------------------------------------
// bf16 GEMM: C[M,N] = A[M,K] @ B[K,N] + bias(f32)
//   EPI==0: store bf16(acc+bias)
//   EPI==1: store f32(acc+bias+f32 resid)   (x + attn@wo)
// 64x64 tile, BK=32, 4 waves. Verified lane maps (cdna_hip_programming.md §3):
//   A[m=lane&15][k=quad*8+j], B[k=quad*8+j][n=lane&15], D[row=quad*4+reg][col=lane&15]
// ---------------------------------------------------------------------------
template <int EPI>
__global__ __launch_bounds__(256) void gemm_k(const u16* __restrict__ A,
                                              const u16* __restrict__ Bm,
                                              const float* __restrict__ bias,
                                              const float* __restrict__ resid,
                                              void* __restrict__ Cout,
                                              int M, int N, int K) {
    __shared__ u16 Al[64 * 40];
    __shared__ u16 Bl[64 * 40];  // B-tile transposed: Bl[n][k]
    const int tid  = threadIdx.x;
    const int m0   = blockIdx.y * 64;
    const int n0   = blockIdx.x * 64;
    const int wave = tid >> 6, lane = tid & 63;
    const int q    = lane >> 4, mr = lane & 15;
    const int ar = tid >> 2, ac = (tid & 3) * 8;   // A tile 64x32
    const int bk = tid >> 3, bc = (tid & 7) * 8;   // B tile 32x64

    fx4 zero = {0.f, 0.f, 0.f, 0.f};
    fx4 acc[4] = {zero, zero, zero, zero};

    for (int k0 = 0; k0 < K; k0 += 32) {
        uint4 av = *(const uint4*)&A[(size_t)(m0 + ar) * K + k0 + ac];
        *(uint4*)&Al[ar * 40 + ac] = av;
        uint4 bv = *(const uint4*)&Bm[(size_t)(k0 + bk) * N + n0 + bc];
        const u16* bp = (const u16*)&bv;
        #pragma unroll
        for (int j = 0; j < 8; ++j) Bl[(bc + j) * 40 + bk] = bp[j];
        __syncthreads();

        bhalf8 af = *(const bhalf8*)&Al[(wave * 16 + mr) * 40 + q * 8];
        #pragma unroll
        for (int nt = 0; nt < 4; ++nt) {
            bhalf8 bf = *(const bhalf8*)&Bl[(nt * 16 + mr) * 40 + q * 8];
            acc[nt] = __builtin_amdgcn_mfma_f32_16x16x32_bf16(af, bf, acc[nt], 0, 0, 0);
        }
        __syncthreads();
    }

    #pragma unroll
    for (int nt = 0; nt < 4; ++nt) {
        int col  = n0 + nt * 16 + mr;
        float bs = bias ? bias[col] : 0.f;
        #pragma unroll
        for (int r = 0; r < 4; ++r) {
            int row    = m0 + wave * 16 + q * 4 + r;
            size_t idx = (size_t)row * N + col;
            float v    = acc[nt][r] + bs;
            if (EPI == 1)
                ((float*)Cout)[idx] = v + resid[idx];
            else
                ((u16*)Cout)[idx] = f2b(v);
        }
    }
}

// ---------------------------------------------------------------------------
// Dual GEMM for QBNN FFN layer:
//   ht = A@W + b ; dlt = tanh(A)@J ; U = ht + 0.5*dlt*tanh(ht)   (bf16 out)
// ---------------------------------------------------------------------------
__global__ __launch_bounds__(256) void qbnn_gemm_k(const u16* __restrict__ A,
                                                   const u16* __restrict__ Wm,
                                                   const u16* __restrict__ Jm,
                                                   const float* __restrict__ bias,
                                                   u16* __restrict__ U,
                                                   int M, int N, int K) {
    __shared__ u16 Ar[64 * 40], At[64 * 40], Wl[64 * 40], Jl[64 * 40];
    const int tid  = threadIdx.x;
    const int m0   = blockIdx.y * 64;
    const int n0   = blockIdx.x * 64;
    const int wave = tid >> 6, lane = tid & 63;
    const int q    = lane >> 4, mr = lane & 15;
    const int ar = tid >> 2, ac = (tid & 3) * 8;
    const int bk = tid >> 3, bc = (tid & 7) * 8;

    fx4 zero = {0.f, 0.f, 0.f, 0.f};
    fx4 aW[4] = {zero, zero, zero, zero};
    fx4 aJ[4] = {zero, zero, zero, zero};

    for (int k0 = 0; k0 < K; k0 += 32) {
        uint4 av = *(const uint4*)&A[(size_t)(m0 + ar) * K + k0 + ac];
        *(uint4*)&Ar[ar * 40 + ac] = av;
        u16 tv[8];
        const u16* ap = (const u16*)&av;
        #pragma unroll
        for (int j = 0; j < 8; ++j) tv[j] = f2b(tanhf(b2f(ap[j])));
        *(uint4*)&At[ar * 40 + ac] = *(uint4*)tv;

        uint4 wv = *(const uint4*)&Wm[(size_t)(k0 + bk) * N + n0 + bc];
        uint4 jv = *(const uint4*)&Jm[(size_t)(k0 + bk) * N + n0 + bc];
        const u16* wp = (const u16*)&wv;
        const u16* jp = (const u16*)&jv;
        #pragma unroll
        for (int j = 0; j < 8; ++j) { Wl[(bc + j) * 40 + bk] = wp[j]; Jl[(bc + j) * 40 + bk] = jp[j]; }
        __syncthreads();

        bhalf8 afr = *(const bhalf8*)&Ar[(wave * 16 + mr) * 40 + q * 8];
        bhalf8 aft = *(const bhalf8*)&At[(wave * 16 + mr) * 40 + q * 8];
        #pragma unroll
        for (int nt = 0; nt < 4; ++nt) {
            bhalf8 wf = *(const bhalf8*)&Wl[(nt * 16 + mr) * 40 + q * 8];
            bhalf8 jf = *(const bhalf8*)&Jl[(nt * 16 + mr) * 40 + q * 8];
            aW[nt] = __builtin_amdgcn_mfma_f32_16x16x32_bf16(afr, wf, aW[nt], 0, 0, 0);
            aJ[nt] = __builtin_amdgcn_mfma_f32_16x16x32_bf16(aft, jf, aJ[nt], 0, 0, 0);
        }
        __syncthreads();
    }

    #pragma unroll
    for (int nt = 0; nt < 4; ++nt) {
        int col  = n0 + nt * 16 + mr;
        float bs = bias[col];
        #pragma unroll
        for (int r = 0; r < 4; ++r) {
            int row    = m0 + wave * 16 + q * 4 + r;
            float ht   = aW[nt][r] + bs;
            float u    = ht + 0.5f * aJ[nt][r] * tanhf(ht);
            U[(size_t)row * N + col] = f2b(u);
        }
    }
}

// ---------------------------------------------------------------------------
// LayerNorm over f32 input rows -> bf16 out. g/b are f32.
// ---------------------------------------------------------------------------
__global__ __launch_bounds__(256) void ln_k(const float* __restrict__ xin,
                                            const float* __restrict__ g,
                                            const float* __restrict__ bb,
                                            u16* __restrict__ out, int W) {
    __shared__ float red[8], red2[8], stats[2];
    int row = blockIdx.x, tid = threadIdx.x;
    float s = 0.f, ss = 0.f;
    for (int c = tid; c < W; c += 256) {
        float v = xin[(size_t)row * W + c];
        s += v; ss += v * v;
    }
    #pragma unroll
    for (int off = 32; off; off >>= 1) { s += __shfl_xor(s, off); ss += __shfl_xor(ss, off); }
    int wave = tid >> 6, lane = tid & 63;
    if (lane == 0) { red[wave] = s; red2[wave] = ss; }
    __syncthreads();
    if (tid == 0) {
        float S = 0.f, SS = 0.f;
        for (int w2 = 0; w2 < 4; ++w2) { S += red[w2]; SS += red2[w2]; }
        float mu = S / W;
        stats[0] = mu;
        stats[1] = rsqrtf(SS / W - mu * mu + 1e-5f);
    }
    __syncthreads();
    float mu = stats[0], rs = stats[1];
    for (int c = tid; c < W; c += 256)
        out[(size_t)row * W + c] = f2b((xin[(size_t)row * W + c] - mu) * rs * g[c] + bb[c]);
}

// ---------------------------------------------------------------------------
// LN + exact GELU over bf16 rows u (already QBNN-combined).
//   RES: add f32 residual.  OUT_F32: store f32 (final output) else bf16.
// In-place safe (out may alias u): all u reads precede the barrier.
// ---------------------------------------------------------------------------
template <bool RES, bool OUT_F32>
__global__ __launch_bounds__(256) void lngelu_k(const u16* __restrict__ u,
                                                const float* __restrict__ g,
                                                const float* __restrict__ be,
                                                const float* __restrict__ resid,
                                                void* __restrict__ out, int W) {
    __shared__ float ub[4096];
    __shared__ float red[8], red2[8], stats[2];
    int row = blockIdx.x, tid = threadIdx.x;
    float s = 0.f, ss = 0.f;
    for (int c = tid; c < W; c += 256) {
        float v = b2f(u[(size_t)row * W + c]);
        ub[c] = v; s += v; ss += v * v;
    }
    #pragma unroll
    for (int off = 32; off; off >>= 1) { s += __shfl_xor(s, off); ss += __shfl_xor(ss, off); }
    int wave = tid >> 6, lane = tid & 63;
    if (lane == 0) { red[wave] = s; red2[wave] = ss; }
    __syncthreads();
    if (tid == 0) {
        float S = 0.f, SS = 0.f;
        for (int w2 = 0; w2 < 4; ++w2) { S += red[w2]; SS += red2[w2]; }
        float mu = S / W;
        stats[0] = mu;
        stats[1] = rsqrtf(SS / W - mu * mu + 1e-5f);
    }
    __syncthreads();
    float mu = stats[0], rs = stats[1];
    for (int c = tid; c < W; c += 256) {
        float v = (ub[c] - mu) * rs * g[c] + be[c];
        float y = 0.5f * v * (1.f + erff(v * 0.70710678118654752f));
        if (RES) y += resid[(size_t)row * W + c];
        if (OUT_F32) ((float*)out)[(size_t)row * W + c] = y;
        else         ((u16*)out)[(size_t)row * W + c] = f2b(y);
    }
}

// ---------------------------------------------------------------------------
// Qaug[B,H,S,128]: [0:64]=Q/8, [64:128]=lam*(tanh(Q)@J[h]).  J,lam are f32.
// ---------------------------------------------------------------------------
__global__ __launch_bounds__(256) void aug_q_k(const u16* __restrict__ Q,
                                               const float* __restrict__ J,
                                               const float* __restrict__ lamp,
                                               u16* __restrict__ QA) {
    __shared__ float Jl[64][65];
    __shared__ float Tq[64][65];
    int blk = blockIdx.x;
    int bh = blk >> 4, st = blk & 15;
    int b = bh >> 4, h = bh & 15;
    int s0 = st * 64;
    int tid = threadIdx.x;
    float lam = lamp[0];

    for (int i = tid; i < 4096; i += 256)
        Jl[i >> 6][i & 63] = J[h * 4096 + i];
    for (int i = tid; i < 4096; i += 256) {
        int r = i >> 6, c = i & 63;
        float v  = b2f(Q[(size_t)(b * S_ + s0 + r) * D_ + h * 64 + c]);
        Tq[r][c] = tanhf(v);
        QA[((size_t)(bh * S_ + s0 + r)) * 128 + c] = f2b(v * 0.125f);  // /sqrt(64)
    }
    __syncthreads();

    int r = tid >> 2, c0 = (tid & 3) * 16;
    float acc[16];
    #pragma unroll
    for (int j = 0; j < 16; ++j) acc[j] = 0.f;
    for (int k = 0; k < 64; ++k) {
        float a = Tq[r][k];
        #pragma unroll
        for (int j = 0; j < 16; ++j) acc[j] += a * Jl[k][c0 + j];
    }
    size_t orow = ((size_t)(bh * S_ + s0 + r)) * 128 + 64 + c0;
    #pragma unroll
    for (int j = 0; j < 16; ++j) QA[orow + j] = f2b(lam * acc[j]);
}

// Kaug[B,H,S,128]: [0:64]=K, [64:128]=tanh(K).
__global__ __launch_bounds__(256) void aug_k_k(const u16* __restrict__ K,
                                               u16* __restrict__ KA) {
    int idx = blockIdx.x * 256 + threadIdx.x;  // < B*S*D
    int d = idx & (D_ - 1);
    int bs = idx >> 10;
    int h = d >> 6, hd = d & 63;
    int b = bs >> 10, si = bs & (S_ - 1);
    u16 v      = K[idx];
    size_t row = (size_t)((b * H_ + h) * S_ + si);
    KA[row * 128 + hd]      = v;
    KA[row * 128 + 64 + hd] = f2b(tanhf(b2f(v)));
}

// ---------------------------------------------------------------------------
// Attention, 128-dim augmented heads, online softmax. One wave per query row.
// ---------------------------------------------------------------------------
__global__ __launch_bounds__(256) void attn_k(const u16* __restrict__ QA,
                                              const u16* __restrict__ KA,
                                              const u16* __restrict__ V,
                                              u16* __restrict__ out) {
    __shared__ float qrow[4][128];
    __shared__ float pbuf[4][64];
    int blk = blockIdx.x, tid = threadIdx.x;
    int w = tid >> 6, lane = tid & 63;
    int bh = blk >> 8, rt = blk & 255;
    int i = rt * 4 + w;
    int b = bh >> 4, h = bh & 15;

    {
        u32 u = *(const u32*)&QA[((size_t)(bh * S_ + i)) * 128 + lane * 2];
        qrow[w][lane * 2]     = b2f((u16)(u & 0xffff));
        qrow[w][lane * 2 + 1] = b2f((u16)(u >> 16));
    }
    __syncthreads();

    float m = -3e38f, lsum = 0.f, o = 0.f;
    for (int jc = 0; jc < 16; ++jc) {
        int j = jc * 64 + lane;
        const uint4* kp = (const uint4*)&KA[((size_t)(bh * S_ + j)) * 128];
        float s = 0.f;
        #pragma unroll
        for (int t = 0; t < 16; ++t) {
            uint4 kv = kp[t];
            fx4 qa = *(const fx4*)&qrow[w][t * 8];
            fx4 qb = *(const fx4*)&qrow[w][t * 8 + 4];
            s += qa[0] * b2f((u16)(kv.x & 0xffff));
            s += qa[1] * b2f((u16)(kv.x >> 16));
            s += qa[2] * b2f((u16)(kv.y & 0xffff));
            s += qa[3] * b2f((u16)(kv.y >> 16));
            s += qb[0] * b2f((u16)(kv.z & 0xffff));
            s += qb[1] * b2f((u16)(kv.z >> 16));
            s += qb[2] * b2f((u16)(kv.w & 0xffff));
            s += qb[3] * b2f((u16)(kv.w >> 16));
        }
        float mx = s;
        #pragma unroll
        for (int off = 32; off; off >>= 1) mx = fmaxf(mx, __shfl_xor(mx, off));
        float nm = fmaxf(m, mx);
        float p  = __expf(s - nm);
        float ps = p;
        #pragma unroll
        for (int off = 32; off; off >>= 1) ps += __shfl_xor(ps, off);
        float alpha = __expf(m - nm);
        lsum = lsum * alpha + ps;
        m    = nm;
        o *= alpha;
        pbuf[w][lane] = p;
        __syncthreads();
        const u16* vp = &V[((size_t)(b * S_ + jc * 64)) * D_ + h * 64 + lane];
        #pragma unroll 8
        for (int jj = 0; jj < 64; ++jj) o += pbuf[w][jj] * b2f(vp[(size_t)jj * D_]);
        __syncthreads();
    }
    out[((size_t)(b * S_ + i)) * D_ + h * 64 + lane] = f2b(o / lsum);
}

// ---------------------------------------------------------------------------
// Workspace plan (104 MB, aliased; live ranges verified):
//   [  0, 40)  WB: bf16 weights (cvt_k output) — live whole launch
//   [ 40, 48)  XN -> Hb
//   [ 48, 56)  Qb -> AT -> U2
//   [ 56, 64)  Kb -+
//   [ 64, 72)  Vb -+-> X2 (f32, 16MB, [56,72))
//   [ 72, 88)  QA -+
//   [ 88,104)  KA -+-> U1/H1 (32MB, [72,104), in-place LN+GELU)
// ---------------------------------------------------------------------------
extern "C" void kernel_launch(void* const* d_in, const int* in_sizes, int n_in,
                              void* d_out, int out_size, void* d_ws, size_t ws_size,
                              hipStream_t stream) {
    const float* x      = (const float*)d_in[0];
    const float* wq     = (const float*)d_in[1];
    const float* bq     = (const float*)d_in[2];
    const float* wk     = (const float*)d_in[3];
    const float* bk     = (const float*)d_in[4];
    const float* wv     = (const float*)d_in[5];
    const float* bv     = (const float*)d_in[6];
    const float* wo     = (const float*)d_in[7];
    const float* bo     = (const float*)d_in[8];
    const float* Jattn  = (const float*)d_in[9];
    const float* lamA   = (const float*)d_in[10];
    const float* g_attn = (const float*)d_in[11];
    const float* b_attn = (const float*)d_in[12];
    const float* W1     = (const float*)d_in[13];
    const float* b1     = (const float*)d_in[14];
    const float* J1     = (const float*)d_in[15];
    const float* g1     = (const float*)d_in[17];
    const float* be1    = (const float*)d_in[18];
    const float* W2     = (const float*)d_in[19];
    const float* b2     = (const float*)d_in[20];
    const float* J2     = (const float*)d_in[21];
    const float* g2     = (const float*)d_in[23];
    const float* be2    = (const float*)d_in[24];
    const float* g_ffn  = (const float*)d_in[25];
    const float* b_ffn  = (const float*)d_in[26];
    float* out = (float*)d_out;
    (void)ws_size; (void)in_sizes; (void)n_in; (void)out_size;

    char* wsp = (char*)d_ws;
    const size_t MB = 1u << 20;
    u16* WB  = (u16*)(wsp + 0 * MB);
    const u16* wqb = WB;
    const u16* wkb = WB + (1u << 20);
    const u16* wvb = WB + (2u << 20);
    const u16* wob = WB + (3u << 20);
    const u16* W1b = WB + ((size_t)4 << 20);
    const u16* J1b = WB + ((size_t)8 << 20);
    const u16* W2b = WB + ((size_t)12 << 20);
    const u16* J2b = WB + ((size_t)16 << 20);
    u16*   XN  = (u16*)(wsp + 40 * MB);
    u16*   Hb  = (u16*)(wsp + 40 * MB);
    u16*   Qb  = (u16*)(wsp + 48 * MB);
    u16*   AT  = (u16*)(wsp + 48 * MB);
    u16*   U2  = (u16*)(wsp + 48 * MB);
    u16*   Kb  = (u16*)(wsp + 56 * MB);
    u16*   Vb  = (u16*)(wsp + 64 * MB);
    float* X2  = (float*)(wsp + 56 * MB);
    u16*   QA  = (u16*)(wsp + 72 * MB);
    u16*   KA  = (u16*)(wsp + 88 * MB);
    u16*   U1  = (u16*)(wsp + 72 * MB);

    dim3 blk(256);
    // 0) weights f32 -> bf16 (20M elems / 8 per thread)
    cvt_k<<<10240, blk, 0, stream>>>(wq, wk, wv, wo, W1, J1, W2, J2, WB);
    // 1) attention pre-norm
    ln_k<<<NTOK, blk, 0, stream>>>(x, g_attn, b_attn, XN, D_);
    // 2) Q,K,V projections
    gemm_k<0><<<dim3(D_ / 64, NTOK / 64), blk, 0, stream>>>(XN, wqb, bq, nullptr, Qb, NTOK, D_, D_);
    gemm_k<0><<<dim3(D_ / 64, NTOK / 64), blk, 0, stream>>>(XN, wkb, bk, nullptr, Kb, NTOK, D_, D_);
    gemm_k<0><<<dim3(D_ / 64, NTOK / 64), blk, 0, stream>>>(XN, wvb, bv, nullptr, Vb, NTOK, D_, D_);
    // 3) augmented heads
    aug_q_k<<<B_ * H_ * (S_ / 64), blk, 0, stream>>>(Qb, Jattn, lamA, QA);
    aug_k_k<<<(NTOK * D_) / 256, blk, 0, stream>>>(Kb, KA);
    // 4) attention (online softmax, head-dim 128)
    attn_k<<<B_ * H_ * (S_ / 4), blk, 0, stream>>>(QA, KA, Vb, AT);
    // 5) output projection + residual -> f32 trunk X2
    gemm_k<1><<<dim3(D_ / 64, NTOK / 64), blk, 0, stream>>>(AT, wob, bo, x, X2, NTOK, D_, D_);
    // 6) ffn pre-norm
    ln_k<<<NTOK, blk, 0, stream>>>(X2, g_ffn, b_ffn, Hb, D_);
    // 7) QBNN layer 1 (dual GEMM + combine), then LN+GELU in-place
    qbnn_gemm_k<<<dim3(FF_ / 64, NTOK / 64), blk, 0, stream>>>(Hb, W1b, J1b, b1, U1, NTOK, FF_, D_);
    lngelu_k<false, false><<<NTOK, blk, 0, stream>>>(U1, g1, be1, nullptr, U1, FF_);
    // 8) QBNN layer 2, then LN+GELU + trunk residual -> f32 out
    qbnn_gemm_k<<<dim3(D_ / 64, NTOK / 64), blk, 0, stream>>>(U1, W2b, J2b, b2, U2, NTOK, D_, FF_);
    lngelu_k<true, true><<<NTOK, blk, 0, stream>>>(U2, g2, be2, X2, out, D_);
}

// Round 4
// 1325.839 us; speedup vs baseline: 2.6121x; 2.6121x over previous
//
#include <hip/hip_runtime.h>
#include <cmath>

typedef unsigned short u16;
typedef unsigned int   u32;
typedef short bhalf8 __attribute__((ext_vector_type(8)));
typedef float fx4    __attribute__((ext_vector_type(4)));

#define B_   4
#define S_   1024
#define D_   1024
#define H_   16
#define HD_  64
#define FF_  4096
#define NTOK (B_*S_)

__device__ __forceinline__ float b2f(u16 u) {
    u32 x = ((u32)u) << 16;
    return __uint_as_float(x);
}
__device__ __forceinline__ u16 f2b(float f) {
    u32 u = __float_as_uint(f);
    u32 r = (u + 0x7fffu + ((u >> 16) & 1u)) >> 16;
    return (u16)r;
}

// ---------------------------------------------------------------------------
// Convert the 8 GEMM weight matrices f32 -> bf16 into one contiguous ws block.
// ---------------------------------------------------------------------------
__global__ __launch_bounds__(256) void cvt_k(const float* __restrict__ w0, const float* __restrict__ w1,
                                             const float* __restrict__ w2, const float* __restrict__ w3,
                                             const float* __restrict__ W1p, const float* __restrict__ J1p,
                                             const float* __restrict__ W2p, const float* __restrict__ J2p,
                                             u16* __restrict__ dst) {
    size_t idx = ((size_t)blockIdx.x * 256 + threadIdx.x) * 8;
    int seg = (int)(idx >> 20);
    const float* src;
    size_t off;
    if (seg < 4)       { src = seg == 0 ? w0 : seg == 1 ? w1 : seg == 2 ? w2 : w3; off = idx & ((1u << 20) - 1); }
    else if (seg < 8)  { src = W1p; off = idx - ((size_t)4 << 20); }
    else if (seg < 12) { src = J1p; off = idx - ((size_t)8 << 20); }
    else if (seg < 16) { src = W2p; off = idx - ((size_t)12 << 20); }
    else               { src = J2p; off = idx - ((size_t)16 << 20); }
    float4 a = *(const float4*)(src + off);
    float4 b = *(const float4*)(src + off + 4);
    u16 r[8] = {f2b(a.x), f2b(a.y), f2b(a.z), f2b(a.w), f2b(b.x), f2b(b.y), f2b(b.z), f2b(b.w)};
    *(uint4*)(dst + idx) = *(uint4*)r;
}

// ---------------------------------------------------------------------------
// bf16 GEMM: C[M,N] = A[M,K] @ B[K,N] + bias(f32)
//   EPI==0: store bf16(acc+bias) ; EPI==1: store f32(acc+bias+f32 resid)
// ---------------------------------------------------------------------------
template <int EPI>
__global__ __launch_bounds__(256) void gemm_k(const u16* __restrict__ A,
                                              const u16* __restrict__ Bm,
                                              const float* __restrict__ bias,
                                              const float* __restrict__ resid,
                                              void* __restrict__ Cout,
                                              int M, int N, int K) {
    __shared__ u16 Al[64 * 40];
    __shared__ u16 Bl[64 * 40];  // B-tile transposed: Bl[n][k]
    const int tid  = threadIdx.x;
    const int m0   = blockIdx.y * 64;
    const int n0   = blockIdx.x * 64;
    const int wave = tid >> 6, lane = tid & 63;
    const int q    = lane >> 4, mr = lane & 15;
    const int ar = tid >> 2, ac = (tid & 3) * 8;
    const int bk = tid >> 3, bc = (tid & 7) * 8;

    fx4 zero = {0.f, 0.f, 0.f, 0.f};
    fx4 acc[4] = {zero, zero, zero, zero};

    for (int k0 = 0; k0 < K; k0 += 32) {
        uint4 av = *(const uint4*)&A[(size_t)(m0 + ar) * K + k0 + ac];
        *(uint4*)&Al[ar * 40 + ac] = av;
        uint4 bv = *(const uint4*)&Bm[(size_t)(k0 + bk) * N + n0 + bc];
        const u16* bp = (const u16*)&bv;
        #pragma unroll
        for (int j = 0; j < 8; ++j) Bl[(bc + j) * 40 + bk] = bp[j];
        __syncthreads();

        bhalf8 af = *(const bhalf8*)&Al[(wave * 16 + mr) * 40 + q * 8];
        #pragma unroll
        for (int nt = 0; nt < 4; ++nt) {
            bhalf8 bf = *(const bhalf8*)&Bl[(nt * 16 + mr) * 40 + q * 8];
            acc[nt] = __builtin_amdgcn_mfma_f32_16x16x32_bf16(af, bf, acc[nt], 0, 0, 0);
        }
        __syncthreads();
    }

    #pragma unroll
    for (int nt = 0; nt < 4; ++nt) {
        int col  = n0 + nt * 16 + mr;
        float bs = bias ? bias[col] : 0.f;
        #pragma unroll
        for (int r = 0; r < 4; ++r) {
            int row    = m0 + wave * 16 + q * 4 + r;
            size_t idx = (size_t)row * N + col;
            float v    = acc[nt][r] + bs;
            if (EPI == 1)
                ((float*)Cout)[idx] = v + resid[idx];
            else
                ((u16*)Cout)[idx] = f2b(v);
        }
    }
}

// ---------------------------------------------------------------------------
// Dual GEMM for QBNN FFN layer:
//   ht = A@W + b ; dlt = tanh(A)@J ; U = ht + 0.5*dlt*tanh(ht)   (bf16 out)
// ---------------------------------------------------------------------------
__global__ __launch_bounds__(256) void qbnn_gemm_k(const u16* __restrict__ A,
                                                   const u16* __restrict__ Wm,
                                                   const u16* __restrict__ Jm,
                                                   const float* __restrict__ bias,
                                                   u16* __restrict__ U,
                                                   int M, int N, int K) {
    __shared__ u16 Ar[64 * 40], At[64 * 40], Wl[64 * 40], Jl[64 * 40];
    const int tid  = threadIdx.x;
    const int m0   = blockIdx.y * 64;
    const int n0   = blockIdx.x * 64;
    const int wave = tid >> 6, lane = tid & 63;
    const int q    = lane >> 4, mr = lane & 15;
    const int ar = tid >> 2, ac = (tid & 3) * 8;
    const int bk = tid >> 3, bc = (tid & 7) * 8;

    fx4 zero = {0.f, 0.f, 0.f, 0.f};
    fx4 aW[4] = {zero, zero, zero, zero};
    fx4 aJ[4] = {zero, zero, zero, zero};

    for (int k0 = 0; k0 < K; k0 += 32) {
        uint4 av = *(const uint4*)&A[(size_t)(m0 + ar) * K + k0 + ac];
        *(uint4*)&Ar[ar * 40 + ac] = av;
        u16 tv[8];
        const u16* ap = (const u16*)&av;
        #pragma unroll
        for (int j = 0; j < 8; ++j) tv[j] = f2b(tanhf(b2f(ap[j])));
        *(uint4*)&At[ar * 40 + ac] = *(uint4*)tv;

        uint4 wv = *(const uint4*)&Wm[(size_t)(k0 + bk) * N + n0 + bc];
        uint4 jv = *(const uint4*)&Jm[(size_t)(k0 + bk) * N + n0 + bc];
        const u16* wp = (const u16*)&wv;
        const u16* jp = (const u16*)&jv;
        #pragma unroll
        for (int j = 0; j < 8; ++j) { Wl[(bc + j) * 40 + bk] = wp[j]; Jl[(bc + j) * 40 + bk] = jp[j]; }
        __syncthreads();

        bhalf8 afr = *(const bhalf8*)&Ar[(wave * 16 + mr) * 40 + q * 8];
        bhalf8 aft = *(const bhalf8*)&At[(wave * 16 + mr) * 40 + q * 8];
        #pragma unroll
        for (int nt = 0; nt < 4; ++nt) {
            bhalf8 wf = *(const bhalf8*)&Wl[(nt * 16 + mr) * 40 + q * 8];
            bhalf8 jf = *(const bhalf8*)&Jl[(nt * 16 + mr) * 40 + q * 8];
            aW[nt] = __builtin_amdgcn_mfma_f32_16x16x32_bf16(afr, wf, aW[nt], 0, 0, 0);
            aJ[nt] = __builtin_amdgcn_mfma_f32_16x16x32_bf16(aft, jf, aJ[nt], 0, 0, 0);
        }
        __syncthreads();
    }

    #pragma unroll
    for (int nt = 0; nt < 4; ++nt) {
        int col  = n0 + nt * 16 + mr;
        float bs = bias[col];
        #pragma unroll
        for (int r = 0; r < 4; ++r) {
            int row    = m0 + wave * 16 + q * 4 + r;
            float ht   = aW[nt][r] + bs;
            float u    = ht + 0.5f * aJ[nt][r] * tanhf(ht);
            U[(size_t)row * N + col] = f2b(u);
        }
    }
}

// ---------------------------------------------------------------------------
// LayerNorm over f32 input rows -> bf16 out.
// ---------------------------------------------------------------------------
__global__ __launch_bounds__(256) void ln_k(const float* __restrict__ xin,
                                            const float* __restrict__ g,
                                            const float* __restrict__ bb,
                                            u16* __restrict__ out, int W) {
    __shared__ float red[8], red2[8], stats[2];
    int row = blockIdx.x, tid = threadIdx.x;
    float s = 0.f, ss = 0.f;
    for (int c = tid; c < W; c += 256) {
        float v = xin[(size_t)row * W + c];
        s += v; ss += v * v;
    }
    #pragma unroll
    for (int off = 32; off; off >>= 1) { s += __shfl_xor(s, off); ss += __shfl_xor(ss, off); }
    int wave = tid >> 6, lane = tid & 63;
    if (lane == 0) { red[wave] = s; red2[wave] = ss; }
    __syncthreads();
    if (tid == 0) {
        float S = 0.f, SS = 0.f;
        for (int w2 = 0; w2 < 4; ++w2) { S += red[w2]; SS += red2[w2]; }
        float mu = S / W;
        stats[0] = mu;
        stats[1] = rsqrtf(SS / W - mu * mu + 1e-5f);
    }
    __syncthreads();
    float mu = stats[0], rs = stats[1];
    for (int c = tid; c < W; c += 256)
        out[(size_t)row * W + c] = f2b((xin[(size_t)row * W + c] - mu) * rs * g[c] + bb[c]);
}

// ---------------------------------------------------------------------------
// LN + exact GELU over bf16 rows u. RES: add f32 resid. OUT_F32: f32 out.
// ---------------------------------------------------------------------------
template <bool RES, bool OUT_F32>
__global__ __launch_bounds__(256) void lngelu_k(const u16* __restrict__ u,
                                                const float* __restrict__ g,
                                                const float* __restrict__ be,
                                                const float* __restrict__ resid,
                                                void* __restrict__ out, int W) {
    __shared__ float ub[4096];
    __shared__ float red[8], red2[8], stats[2];
    int row = blockIdx.x, tid = threadIdx.x;
    float s = 0.f, ss = 0.f;
    for (int c = tid; c < W; c += 256) {
        float v = b2f(u[(size_t)row * W + c]);
        ub[c] = v; s += v; ss += v * v;
    }
    #pragma unroll
    for (int off = 32; off; off >>= 1) { s += __shfl_xor(s, off); ss += __shfl_xor(ss, off); }
    int wave = tid >> 6, lane = tid & 63;
    if (lane == 0) { red[wave] = s; red2[wave] = ss; }
    __syncthreads();
    if (tid == 0) {
        float S = 0.f, SS = 0.f;
        for (int w2 = 0; w2 < 4; ++w2) { S += red[w2]; SS += red2[w2]; }
        float mu = S / W;
        stats[0] = mu;
        stats[1] = rsqrtf(SS / W - mu * mu + 1e-5f);
    }
    __syncthreads();
    float mu = stats[0], rs = stats[1];
    for (int c = tid; c < W; c += 256) {
        float v = (ub[c] - mu) * rs * g[c] + be[c];
        float y = 0.5f * v * (1.f + erff(v * 0.70710678118654752f));
        if (RES) y += resid[(size_t)row * W + c];
        if (OUT_F32) ((float*)out)[(size_t)row * W + c] = y;
        else         ((u16*)out)[(size_t)row * W + c] = f2b(y);
    }
}

// ---------------------------------------------------------------------------
// Qaug[B,H,S,128]: [0:64]=Q/8, [64:128]=lam*(tanh(Q)@J[h]).
// ---------------------------------------------------------------------------
__global__ __launch_bounds__(256) void aug_q_k(const u16* __restrict__ Q,
                                               const float* __restrict__ J,
                                               const float* __restrict__ lamp,
                                               u16* __restrict__ QA) {
    __shared__ float Jl[64][65];
    __shared__ float Tq[64][65];
    int blk = blockIdx.x;
    int bh = blk >> 4, st = blk & 15;
    int b = bh >> 4, h = bh & 15;
    int s0 = st * 64;
    int tid = threadIdx.x;
    float lam = lamp[0];

    for (int i = tid; i < 4096; i += 256)
        Jl[i >> 6][i & 63] = J[h * 4096 + i];
    for (int i = tid; i < 4096; i += 256) {
        int r = i >> 6, c = i & 63;
        float v  = b2f(Q[(size_t)(b * S_ + s0 + r) * D_ + h * 64 + c]);
        Tq[r][c] = tanhf(v);
        QA[((size_t)(bh * S_ + s0 + r)) * 128 + c] = f2b(v * 0.125f);  // /sqrt(64)
    }
    __syncthreads();

    int r = tid >> 2, c0 = (tid & 3) * 16;
    float acc[16];
    #pragma unroll
    for (int j = 0; j < 16; ++j) acc[j] = 0.f;
    for (int k = 0; k < 64; ++k) {
        float a = Tq[r][k];
        #pragma unroll
        for (int j = 0; j < 16; ++j) acc[j] += a * Jl[k][c0 + j];
    }
    size_t orow = ((size_t)(bh * S_ + s0 + r)) * 128 + 64 + c0;
    #pragma unroll
    for (int j = 0; j < 16; ++j) QA[orow + j] = f2b(lam * acc[j]);
}

// Kaug[B,H,S,128]: [0:64]=K, [64:128]=tanh(K).
__global__ __launch_bounds__(256) void aug_k_k(const u16* __restrict__ K,
                                               u16* __restrict__ KA) {
    int idx = blockIdx.x * 256 + threadIdx.x;
    int d = idx & (D_ - 1);
    int bs = idx >> 10;
    int h = d >> 6, hd = d & 63;
    int b = bs >> 10, si = bs & (S_ - 1);
    u16 v      = K[idx];
    size_t row = (size_t)((b * H_ + h) * S_ + si);
    KA[row * 128 + hd]      = v;
    KA[row * 128 + 64 + hd] = f2b(tanhf(b2f(v)));
}

// ---------------------------------------------------------------------------
// MFMA flash attention, augmented head-dim 128, keys in 64-row tiles.
// Block = (b,h, 64-row Q tile); 4 waves, each wave owns 16 Q rows.
// Layouts per verified 16x16x32 maps:
//   A[m=lane&15][k=quad*8+j], B[k=quad*8+j][n=lane&15], D[row=quad*4+reg][col=lane&15]
// P (C-layout) -> LDS -> A-layout round trip for the PV MFMA (m120 pattern).
// ---------------------------------------------------------------------------
#define QS_STRIDE 136   // 272 B, 16B-aligned
#define PS_STRIDE 72    // 144 B, 16B-aligned
__global__ __launch_bounds__(256) void attn_k(const u16* __restrict__ QA,
                                              const u16* __restrict__ KA,
                                              const u16* __restrict__ V,
                                              u16* __restrict__ out) {
    __shared__ u16 Qs[64 * QS_STRIDE];
    __shared__ u16 Ks[64 * QS_STRIDE];
    __shared__ u16 Vt[64 * PS_STRIDE];       // Vt[d][key]
    __shared__ u16 Ps[4 * 16 * PS_STRIDE];   // per-wave P tile [16 rows][64 keys]

    const int tid  = threadIdx.x;
    const int w    = tid >> 6, lane = tid & 63;
    const int q    = lane >> 4, mr = lane & 15;
    const int bh   = blockIdx.x >> 4;        // b*H + h
    const int qt   = blockIdx.x & 15;
    const int b    = bh >> 4, h = bh & 15;

    // stage Q tile: 64 rows x 128
    #pragma unroll
    for (int p = 0; p < 4; ++p) {
        int idx = p * 2048 + tid * 8;
        int row = idx >> 7, col = idx & 127;
        uint4 v4 = *(const uint4*)&QA[((size_t)(bh * S_ + qt * 64 + row)) * 128 + col];
        *(uint4*)&Qs[row * QS_STRIDE + col] = v4;
    }

    fx4 zero = {0.f, 0.f, 0.f, 0.f};
    fx4 O[4] = {zero, zero, zero, zero};
    float m[4]  = {-3e38f, -3e38f, -3e38f, -3e38f};
    float l[4]  = {0.f, 0.f, 0.f, 0.f};

    for (int kt = 0; kt < 16; ++kt) {
        // stage K tile (64x128) and V tile transposed (Vt[d][key])
        #pragma unroll
        for (int p = 0; p < 4; ++p) {
            int idx = p * 2048 + tid * 8;
            int row = idx >> 7, col = idx & 127;
            uint4 v4 = *(const uint4*)&KA[((size_t)(bh * S_ + kt * 64 + row)) * 128 + col];
            *(uint4*)&Ks[row * QS_STRIDE + col] = v4;
        }
        #pragma unroll
        for (int p = 0; p < 2; ++p) {
            int idx = p * 2048 + tid * 8;
            int key = idx >> 6, d0 = idx & 63;
            uint4 v4 = *(const uint4*)&V[((size_t)(b * S_ + kt * 64 + key)) * D_ + h * 64 + d0];
            const u16* vp = (const u16*)&v4;
            #pragma unroll
            for (int j = 0; j < 8; ++j) Vt[(d0 + j) * PS_STRIDE + key] = vp[j];
        }
        __syncthreads();

        // S = Qaug @ Kaug^T  (wave's 16 rows x 64 keys)
        fx4 St[4] = {zero, zero, zero, zero};
        bhalf8 afr[4];
        #pragma unroll
        for (int ks = 0; ks < 4; ++ks)
            afr[ks] = *(const bhalf8*)&Qs[(w * 16 + mr) * QS_STRIDE + ks * 32 + q * 8];
        #pragma unroll
        for (int nt = 0; nt < 4; ++nt) {
            #pragma unroll
            for (int ks = 0; ks < 4; ++ks) {
                bhalf8 bf = *(const bhalf8*)&Ks[(nt * 16 + mr) * QS_STRIDE + ks * 32 + q * 8];
                St[nt] = __builtin_amdgcn_mfma_f32_16x16x32_bf16(afr[ks], bf, St[nt], 0, 0, 0);
            }
        }

        // online softmax (rows = q*4+r; cols spread over 16 lanes x 4 nt)
        float alpha[4];
        #pragma unroll
        for (int r = 0; r < 4; ++r) {
            float mx = fmaxf(fmaxf(St[0][r], St[1][r]), fmaxf(St[2][r], St[3][r]));
            #pragma unroll
            for (int off = 8; off; off >>= 1) mx = fmaxf(mx, __shfl_xor(mx, off));
            float nm = fmaxf(m[r], mx);
            alpha[r] = __expf(m[r] - nm);
            m[r] = nm;
            float ps = 0.f;
            #pragma unroll
            for (int nt = 0; nt < 4; ++nt) {
                float p = __expf(St[nt][r] - nm);
                St[nt][r] = p;
                ps += p;
            }
            #pragma unroll
            for (int off = 8; off; off >>= 1) ps += __shfl_xor(ps, off);
            l[r] = l[r] * alpha[r] + ps;
        }
        // write P (bf16) to this wave's LDS tile; rescale O
        #pragma unroll
        for (int nt = 0; nt < 4; ++nt) {
            #pragma unroll
            for (int r = 0; r < 4; ++r) {
                Ps[(w * 16 + q * 4 + r) * PS_STRIDE + nt * 16 + mr] = f2b(St[nt][r]);
                O[nt][r] *= alpha[r];
            }
        }

        // O += P @ V   (A = Ps[m][k], B = Vt[n][k])
        #pragma unroll
        for (int ks = 0; ks < 2; ++ks) {
            bhalf8 pa = *(const bhalf8*)&Ps[(w * 16 + mr) * PS_STRIDE + ks * 32 + q * 8];
            #pragma unroll
            for (int nt = 0; nt < 4; ++nt) {
                bhalf8 bf = *(const bhalf8*)&Vt[(nt * 16 + mr) * PS_STRIDE + ks * 32 + q * 8];
                O[nt] = __builtin_amdgcn_mfma_f32_16x16x32_bf16(pa, bf, O[nt], 0, 0, 0);
            }
        }
        __syncthreads();
    }

    // epilogue: out[row][d] = O/l
    #pragma unroll
    for (int nt = 0; nt < 4; ++nt) {
        int d = nt * 16 + mr;
        #pragma unroll
        for (int r = 0; r < 4; ++r) {
            int row = qt * 64 + w * 16 + q * 4 + r;
            out[((size_t)(b * S_ + row)) * D_ + h * 64 + d] = f2b(O[nt][r] / l[r]);
        }
    }
}

// ---------------------------------------------------------------------------
// Workspace plan (104 MB, aliased; live ranges verified):
//   [  0, 40)  WB: bf16 weights — live whole launch
//   [ 40, 48)  XN -> Hb
//   [ 48, 56)  Qb -> AT -> U2
//   [ 56, 64)  Kb -+
//   [ 64, 72)  Vb -+-> X2 (f32, 16MB, [56,72))
//   [ 72, 88)  QA -+
//   [ 88,104)  KA -+-> U1/H1 (32MB, [72,104), in-place LN+GELU)
// ---------------------------------------------------------------------------
extern "C" void kernel_launch(void* const* d_in, const int* in_sizes, int n_in,
                              void* d_out, int out_size, void* d_ws, size_t ws_size,
                              hipStream_t stream) {
    const float* x      = (const float*)d_in[0];
    const float* wq     = (const float*)d_in[1];
    const float* bq     = (const float*)d_in[2];
    const float* wk     = (const float*)d_in[3];
    const float* bk     = (const float*)d_in[4];
    const float* wv     = (const float*)d_in[5];
    const float* bv     = (const float*)d_in[6];
    const float* wo     = (const float*)d_in[7];
    const float* bo     = (const float*)d_in[8];
    const float* Jattn  = (const float*)d_in[9];
    const float* lamA   = (const float*)d_in[10];
    const float* g_attn = (const float*)d_in[11];
    const float* b_attn = (const float*)d_in[12];
    const float* W1     = (const float*)d_in[13];
    const float* b1     = (const float*)d_in[14];
    const float* J1     = (const float*)d_in[15];
    const float* g1     = (const float*)d_in[17];
    const float* be1    = (const float*)d_in[18];
    const float* W2     = (const float*)d_in[19];
    const float* b2     = (const float*)d_in[20];
    const float* J2     = (const float*)d_in[21];
    const float* g2     = (const float*)d_in[23];
    const float* be2    = (const float*)d_in[24];
    const float* g_ffn  = (const float*)d_in[25];
    const float* b_ffn  = (const float*)d_in[26];
    float* out = (float*)d_out;
    (void)ws_size; (void)in_sizes; (void)n_in; (void)out_size;

    char* wsp = (char*)d_ws;
    const size_t MB = 1u << 20;
    u16* WB  = (u16*)(wsp + 0 * MB);
    const u16* wqb = WB;
    const u16* wkb = WB + (1u << 20);
    const u16* wvb = WB + (2u << 20);
    const u16* wob = WB + (3u << 20);
    const u16* W1b = WB + ((size_t)4 << 20);
    const u16* J1b = WB + ((size_t)8 << 20);
    const u16* W2b = WB + ((size_t)12 << 20);
    const u16* J2b = WB + ((size_t)16 << 20);
    u16*   XN  = (u16*)(wsp + 40 * MB);
    u16*   Hb  = (u16*)(wsp + 40 * MB);
    u16*   Qb  = (u16*)(wsp + 48 * MB);
    u16*   AT  = (u16*)(wsp + 48 * MB);
    u16*   U2  = (u16*)(wsp + 48 * MB);
    u16*   Kb  = (u16*)(wsp + 56 * MB);
    u16*   Vb  = (u16*)(wsp + 64 * MB);
    float* X2  = (float*)(wsp + 56 * MB);
    u16*   QA  = (u16*)(wsp + 72 * MB);
    u16*   KA  = (u16*)(wsp + 88 * MB);
    u16*   U1  = (u16*)(wsp + 72 * MB);

    dim3 blk(256);
    // 0) weights f32 -> bf16
    cvt_k<<<10240, blk, 0, stream>>>(wq, wk, wv, wo, W1, J1, W2, J2, WB);
    // 1) attention pre-norm
    ln_k<<<NTOK, blk, 0, stream>>>(x, g_attn, b_attn, XN, D_);
    // 2) Q,K,V projections
    gemm_k<0><<<dim3(D_ / 64, NTOK / 64), blk, 0, stream>>>(XN, wqb, bq, nullptr, Qb, NTOK, D_, D_);
    gemm_k<0><<<dim3(D_ / 64, NTOK / 64), blk, 0, stream>>>(XN, wkb, bk, nullptr, Kb, NTOK, D_, D_);
    gemm_k<0><<<dim3(D_ / 64, NTOK / 64), blk, 0, stream>>>(XN, wvb, bv, nullptr, Vb, NTOK, D_, D_);
    // 3) augmented heads
    aug_q_k<<<B_ * H_ * (S_ / 64), blk, 0, stream>>>(Qb, Jattn, lamA, QA);
    aug_k_k<<<(NTOK * D_) / 256, blk, 0, stream>>>(Kb, KA);
    // 4) MFMA flash attention
    attn_k<<<B_ * H_ * (S_ / 64), blk, 0, stream>>>(QA, KA, Vb, AT);
    // 5) output projection + residual -> f32 trunk X2
    gemm_k<1><<<dim3(D_ / 64, NTOK / 64), blk, 0, stream>>>(AT, wob, bo, x, X2, NTOK, D_, D_);
    // 6) ffn pre-norm
    ln_k<<<NTOK, blk, 0, stream>>>(X2, g_ffn, b_ffn, Hb, D_);
    // 7) QBNN layer 1 (dual GEMM + combine), then LN+GELU in-place
    qbnn_gemm_k<<<dim3(FF_ / 64, NTOK / 64), blk, 0, stream>>>(Hb, W1b, J1b, b1, U1, NTOK, FF_, D_);
    lngelu_k<false, false><<<NTOK, blk, 0, stream>>>(U1, g1, be1, nullptr, U1, FF_);
    // 8) QBNN layer 2, then LN+GELU + trunk residual -> f32 out
    qbnn_gemm_k<<<dim3(D_ / 64, NTOK / 64), blk, 0, stream>>>(U1, W2b, J2b, b2, U2, NTOK, D_, FF_);
    lngelu_k<true, true><<<NTOK, blk, 0, stream>>>(U2, g2, be2, X2, out, D_);
}

// Round 5
// 1043.737 us; speedup vs baseline: 3.3181x; 1.2703x over previous
//
#include <hip/hip_runtime.h>
#include <cmath>

typedef unsigned short u16;
typedef unsigned int   u32;
typedef short bhalf8 __attribute__((ext_vector_type(8)));
typedef float fx4    __attribute__((ext_vector_type(4)));

#define B_   4
#define S_   1024
#define D_   1024
#define H_   16
#define HD_  64
#define FF_  4096
#define NTOK (B_*S_)

__device__ __forceinline__ float b2f(u16 u) {
    u32 x = ((u32)u) << 16;
    return __uint_as_float(x);
}
__device__ __forceinline__ u16 f2b(float f) {
    u32 u = __float_as_uint(f);
    u32 r = (u + 0x7fffu + ((u >> 16) & 1u)) >> 16;
    return (u16)r;
}

// async global->LDS, 16B per lane; LDS dest = wave-uniform base + lane*16
#define GLDS16(g, l) __builtin_amdgcn_global_load_lds( \
    (const __attribute__((address_space(1))) void*)(g), \
    (__attribute__((address_space(3))) void*)(l), 16, 0, 0)

// ---------------------------------------------------------------------------
// Weight convert + transpose: f32 [K,N] -> bf16 [N,K] tiles of 64x64.
// Dst elem offsets: wq 0, wk 1M, wv 2M, wo 3M, W1 4M, J1 8M, W2 12M, J2 16M.
// ---------------------------------------------------------------------------
__global__ __launch_bounds__(256) void cvt_t_k(const float* __restrict__ w0, const float* __restrict__ w1,
                                               const float* __restrict__ w2, const float* __restrict__ w3,
                                               const float* __restrict__ W1p, const float* __restrict__ J1p,
                                               const float* __restrict__ W2p, const float* __restrict__ J2p,
                                               u16* __restrict__ dst) {
    __shared__ u16 L[64][65];
    int bid = blockIdx.x, tid = threadIdx.x;
    const float* src; size_t dbase; int Kd, Nd, tk, tn;
    if (bid < 1024)      { int m = bid >> 8, t = bid & 255;
                           src = m == 0 ? w0 : m == 1 ? w1 : m == 2 ? w2 : w3;
                           dbase = (size_t)m << 20; Kd = 1024; Nd = 1024; tk = t >> 4; tn = t & 15; }
    else if (bid < 2048) { int t = bid - 1024; src = W1p; dbase = (size_t)4  << 20; Kd = 1024; Nd = 4096; tk = t >> 6; tn = t & 63; }
    else if (bid < 3072) { int t = bid - 2048; src = J1p; dbase = (size_t)8  << 20; Kd = 1024; Nd = 4096; tk = t >> 6; tn = t & 63; }
    else if (bid < 4096) { int t = bid - 3072; src = W2p; dbase = (size_t)12 << 20; Kd = 4096; Nd = 1024; tk = t >> 4; tn = t & 15; }
    else                 { int t = bid - 4096; src = J2p; dbase = (size_t)16 << 20; Kd = 4096; Nd = 1024; tk = t >> 4; tn = t & 15; }
    int k0 = tk * 64, n0 = tn * 64;
    int r = tid >> 2, c4 = (tid & 3) * 16;
    #pragma unroll
    for (int p = 0; p < 4; ++p) {
        float4 v = *(const float4*)&src[(size_t)(k0 + r) * Nd + n0 + c4 + p * 4];
        L[r][c4 + p * 4 + 0] = f2b(v.x);
        L[r][c4 + p * 4 + 1] = f2b(v.y);
        L[r][c4 + p * 4 + 2] = f2b(v.z);
        L[r][c4 + p * 4 + 3] = f2b(v.w);
    }
    __syncthreads();
    u16 o[16];
    #pragma unroll
    for (int j = 0; j < 16; ++j) o[j] = L[c4 + j][r];
    *(uint4*)&dst[dbase + (size_t)(n0 + r) * Kd + k0 + c4]     = *(uint4*)&o[0];
    *(uint4*)&dst[dbase + (size_t)(n0 + r) * Kd + k0 + c4 + 8] = *(uint4*)&o[8];
}

// ---------------------------------------------------------------------------
// 128x128 MFMA GEMM (m97 structure): C[M,N] = op(A)[M,K] @ Bt[N,K]^T + bias
//   TANH_A: stage tanh(A) (manual vector load + ds_write; B still via glds)
//   EPI 0: store bf16(acc+bias)
//   EPI 1: store f32(acc+bias+resid)        (x + attn@wo)
//   EPI 2: ht=Cout[idx]; Cout=bf16(ht+0.5*acc*tanh(ht))   (QBNN combine)
// 4 waves in 2x2; each wave 64x64 via 4x4 of 16x16x32 MFMA. BK=32.
// LDS: As/Bs 128x32 u16 (no pad — global_load_lds lane-order constraint).
// Verified lane maps: A[m=lane&15][k=q*8+j], B[k][n=lane&15], D[row=q*4+r][col=lane&15].
// ---------------------------------------------------------------------------
template <bool TANH_A, int EPI>
__global__ __launch_bounds__(256, 2) void gemm128(const u16* __restrict__ A,
                                                  const u16* __restrict__ Bt,
                                                  const float* __restrict__ bias,
                                                  const float* __restrict__ resid,
                                                  void* __restrict__ Cout,
                                                  int M, int N, int K) {
    __shared__ u16 As[128 * 32];
    __shared__ u16 Bs[128 * 32];
    const int tid = threadIdx.x;
    const int w = tid >> 6, ln = tid & 63;
    const int q = ln >> 4, mr = ln & 15;
    const int m0 = blockIdx.y * 128, n0 = blockIdx.x * 128;
    const int wm = (w >> 1) * 64, wn = (w & 1) * 64;
    const int sr = w * 16 + (ln >> 2);   // staging row (chunk w)
    const int sc = (ln & 3) * 8;         // staging col

    fx4 acc[4][4];
    #pragma unroll
    for (int i = 0; i < 4; ++i)
        #pragma unroll
        for (int j = 0; j < 4; ++j) acc[i][j] = (fx4){0.f, 0.f, 0.f, 0.f};

    const u16* Ab0 = A  + (size_t)(m0 + sr) * K + sc;
    const u16* Ab1 = A  + (size_t)(m0 + sr + 64) * K + sc;
    const u16* Bb0 = Bt + (size_t)(n0 + sr) * K + sc;
    const u16* Bb1 = Bt + (size_t)(n0 + sr + 64) * K + sc;

    for (int k0 = 0; k0 < K; k0 += 32) {
        __syncthreads();   // prior reads done before overwrite
        if (!TANH_A) {
            GLDS16(Ab0 + k0, &As[w * 512]);
            GLDS16(Ab1 + k0, &As[(w + 4) * 512]);
        } else {
            uint4 a0 = *(const uint4*)(Ab0 + k0);
            uint4 a1 = *(const uint4*)(Ab1 + k0);
            const u16* p0 = (const u16*)&a0;
            const u16* p1 = (const u16*)&a1;
            u16 t0[8], t1[8];
            #pragma unroll
            for (int j = 0; j < 8; ++j) {
                t0[j] = f2b(tanhf(b2f(p0[j])));
                t1[j] = f2b(tanhf(b2f(p1[j])));
            }
            *(uint4*)&As[w * 512 + ln * 8]       = *(uint4*)t0;
            *(uint4*)&As[(w + 4) * 512 + ln * 8] = *(uint4*)t1;
        }
        GLDS16(Bb0 + k0, &Bs[w * 512]);
        GLDS16(Bb1 + k0, &Bs[(w + 4) * 512]);
        __syncthreads();   // drains vmcnt/lgkm: staged data visible

        bhalf8 af[4], bf[4];
        #pragma unroll
        for (int i = 0; i < 4; ++i) af[i] = *(const bhalf8*)&As[(wm + i * 16 + mr) * 32 + q * 8];
        #pragma unroll
        for (int j = 0; j < 4; ++j) bf[j] = *(const bhalf8*)&Bs[(wn + j * 16 + mr) * 32 + q * 8];
        #pragma unroll
        for (int i = 0; i < 4; ++i)
            #pragma unroll
            for (int j = 0; j < 4; ++j)
                acc[i][j] = __builtin_amdgcn_mfma_f32_16x16x32_bf16(af[i], bf[j], acc[i][j], 0, 0, 0);
    }

    #pragma unroll
    for (int j = 0; j < 4; ++j) {
        int col  = n0 + wn + j * 16 + mr;
        float bs = bias ? bias[col] : 0.f;
        #pragma unroll
        for (int i = 0; i < 4; ++i) {
            #pragma unroll
            for (int r = 0; r < 4; ++r) {
                int row    = m0 + wm + i * 16 + q * 4 + r;
                size_t idx = (size_t)row * N + col;
                float v    = acc[i][j][r] + bs;
                if (EPI == 0) {
                    ((u16*)Cout)[idx] = f2b(v);
                } else if (EPI == 1) {
                    ((float*)Cout)[idx] = v + resid[idx];
                } else {
                    float ht = b2f(((u16*)Cout)[idx]);
                    ((u16*)Cout)[idx] = f2b(ht + 0.5f * v * tanhf(ht));
                }
            }
        }
    }
}

// ---------------------------------------------------------------------------
// LayerNorm over f32 input rows -> bf16 out.
// ---------------------------------------------------------------------------
__global__ __launch_bounds__(256) void ln_k(const float* __restrict__ xin,
                                            const float* __restrict__ g,
                                            const float* __restrict__ bb,
                                            u16* __restrict__ out, int W) {
    __shared__ float red[8], red2[8], stats[2];
    int row = blockIdx.x, tid = threadIdx.x;
    float s = 0.f, ss = 0.f;
    for (int c = tid; c < W; c += 256) {
        float v = xin[(size_t)row * W + c];
        s += v; ss += v * v;
    }
    #pragma unroll
    for (int off = 32; off; off >>= 1) { s += __shfl_xor(s, off); ss += __shfl_xor(ss, off); }
    int wave = tid >> 6, lane = tid & 63;
    if (lane == 0) { red[wave] = s; red2[wave] = ss; }
    __syncthreads();
    if (tid == 0) {
        float S = 0.f, SS = 0.f;
        for (int w2 = 0; w2 < 4; ++w2) { S += red[w2]; SS += red2[w2]; }
        float mu = S / W;
        stats[0] = mu;
        stats[1] = rsqrtf(SS / W - mu * mu + 1e-5f);
    }
    __syncthreads();
    float mu = stats[0], rs = stats[1];
    for (int c = tid; c < W; c += 256)
        out[(size_t)row * W + c] = f2b((xin[(size_t)row * W + c] - mu) * rs * g[c] + bb[c]);
}

// ---------------------------------------------------------------------------
// LN + exact GELU over bf16 rows u. RES: add f32 resid. OUT_F32: f32 out.
// In-place safe: all u reads precede the barrier before writes.
// ---------------------------------------------------------------------------
template <bool RES, bool OUT_F32>
__global__ __launch_bounds__(256) void lngelu_k(const u16* __restrict__ u,
                                                const float* __restrict__ g,
                                                const float* __restrict__ be,
                                                const float* __restrict__ resid,
                                                void* __restrict__ out, int W) {
    __shared__ float ub[4096];
    __shared__ float red[8], red2[8], stats[2];
    int row = blockIdx.x, tid = threadIdx.x;
    float s = 0.f, ss = 0.f;
    for (int c = tid; c < W; c += 256) {
        float v = b2f(u[(size_t)row * W + c]);
        ub[c] = v; s += v; ss += v * v;
    }
    #pragma unroll
    for (int off = 32; off; off >>= 1) { s += __shfl_xor(s, off); ss += __shfl_xor(ss, off); }
    int wave = tid >> 6, lane = tid & 63;
    if (lane == 0) { red[wave] = s; red2[wave] = ss; }
    __syncthreads();
    if (tid == 0) {
        float S = 0.f, SS = 0.f;
        for (int w2 = 0; w2 < 4; ++w2) { S += red[w2]; SS += red2[w2]; }
        float mu = S / W;
        stats[0] = mu;
        stats[1] = rsqrtf(SS / W - mu * mu + 1e-5f);
    }
    __syncthreads();
    float mu = stats[0], rs = stats[1];
    for (int c = tid; c < W; c += 256) {
        float v = (ub[c] - mu) * rs * g[c] + be[c];
        float y = 0.5f * v * (1.f + erff(v * 0.70710678118654752f));
        if (RES) y += resid[(size_t)row * W + c];
        if (OUT_F32) ((float*)out)[(size_t)row * W + c] = y;
        else         ((u16*)out)[(size_t)row * W + c] = f2b(y);
    }
}

// ---------------------------------------------------------------------------
// Qaug[B,H,S,128]: [0:64]=Q/8, [64:128]=lam*(tanh(Q)@J[h]).
// ---------------------------------------------------------------------------
__global__ __launch_bounds__(256) void aug_q_k(const u16* __restrict__ Q,
                                               const float* __restrict__ J,
                                               const float* __restrict__ lamp,
                                               u16* __restrict__ QA) {
    __shared__ float Jl[64][65];
    __shared__ float Tq[64][65];
    int blk = blockIdx.x;
    int bh = blk >> 4, st = blk & 15;
    int b = bh >> 4, h = bh & 15;
    int s0 = st * 64;
    int tid = threadIdx.x;
    float lam = lamp[0];

    for (int i = tid; i < 4096; i += 256)
        Jl[i >> 6][i & 63] = J[h * 4096 + i];
    for (int i = tid; i < 4096; i += 256) {
        int r = i >> 6, c = i & 63;
        float v  = b2f(Q[(size_t)(b * S_ + s0 + r) * D_ + h * 64 + c]);
        Tq[r][c] = tanhf(v);
        QA[((size_t)(bh * S_ + s0 + r)) * 128 + c] = f2b(v * 0.125f);  // /sqrt(64)
    }
    __syncthreads();

    int r = tid >> 2, c0 = (tid & 3) * 16;
    float acc[16];
    #pragma unroll
    for (int j = 0; j < 16; ++j) acc[j] = 0.f;
    for (int k = 0; k < 64; ++k) {
        float a = Tq[r][k];
        #pragma unroll
        for (int j = 0; j < 16; ++j) acc[j] += a * Jl[k][c0 + j];
    }
    size_t orow = ((size_t)(bh * S_ + s0 + r)) * 128 + 64 + c0;
    #pragma unroll
    for (int j = 0; j < 16; ++j) QA[orow + j] = f2b(lam * acc[j]);
}

// Kaug[B,H,S,128]: [0:64]=K, [64:128]=tanh(K).
__global__ __launch_bounds__(256) void aug_k_k(const u16* __restrict__ K,
                                               u16* __restrict__ KA) {
    int idx = blockIdx.x * 256 + threadIdx.x;
    int d = idx & (D_ - 1);
    int bs = idx >> 10;
    int h = d >> 6, hd = d & 63;
    int b = bs >> 10, si = bs & (S_ - 1);
    u16 v      = K[idx];
    size_t row = (size_t)((b * H_ + h) * S_ + si);
    KA[row * 128 + hd]      = v;
    KA[row * 128 + 64 + hd] = f2b(tanhf(b2f(v)));
}

// ---------------------------------------------------------------------------
// MFMA flash attention, augmented head-dim 128, keys in 64-row tiles.
// ---------------------------------------------------------------------------
#define QS_STRIDE 136
#define PS_STRIDE 72
__global__ __launch_bounds__(256) void attn_k(const u16* __restrict__ QA,
                                              const u16* __restrict__ KA,
                                              const u16* __restrict__ V,
                                              u16* __restrict__ out) {
    __shared__ u16 Qs[64 * QS_STRIDE];
    __shared__ u16 Ks[64 * QS_STRIDE];
    __shared__ u16 Vt[64 * PS_STRIDE];
    __shared__ u16 Ps[4 * 16 * PS_STRIDE];

    const int tid  = threadIdx.x;
    const int w    = tid >> 6, lane = tid & 63;
    const int q    = lane >> 4, mr = lane & 15;
    const int bh   = blockIdx.x >> 4;
    const int qt   = blockIdx.x & 15;
    const int b    = bh >> 4, h = bh & 15;

    #pragma unroll
    for (int p = 0; p < 4; ++p) {
        int idx = p * 2048 + tid * 8;
        int row = idx >> 7, col = idx & 127;
        uint4 v4 = *(const uint4*)&QA[((size_t)(bh * S_ + qt * 64 + row)) * 128 + col];
        *(uint4*)&Qs[row * QS_STRIDE + col] = v4;
    }

    fx4 zero = {0.f, 0.f, 0.f, 0.f};
    fx4 O[4] = {zero, zero, zero, zero};
    float m[4]  = {-3e38f, -3e38f, -3e38f, -3e38f};
    float l[4]  = {0.f, 0.f, 0.f, 0.f};

    for (int kt = 0; kt < 16; ++kt) {
        #pragma unroll
        for (int p = 0; p < 4; ++p) {
            int idx = p * 2048 + tid * 8;
            int row = idx >> 7, col = idx & 127;
            uint4 v4 = *(const uint4*)&KA[((size_t)(bh * S_ + kt * 64 + row)) * 128 + col];
            *(uint4*)&Ks[row * QS_STRIDE + col] = v4;
        }
        #pragma unroll
        for (int p = 0; p < 2; ++p) {
            int idx = p * 2048 + tid * 8;
            int key = idx >> 6, d0 = idx & 63;
            uint4 v4 = *(const uint4*)&V[((size_t)(b * S_ + kt * 64 + key)) * D_ + h * 64 + d0];
            const u16* vp = (const u16*)&v4;
            #pragma unroll
            for (int j = 0; j < 8; ++j) Vt[(d0 + j) * PS_STRIDE + key] = vp[j];
        }
        __syncthreads();

        fx4 St[4] = {zero, zero, zero, zero};
        bhalf8 afr[4];
        #pragma unroll
        for (int ks = 0; ks < 4; ++ks)
            afr[ks] = *(const bhalf8*)&Qs[(w * 16 + mr) * QS_STRIDE + ks * 32 + q * 8];
        #pragma unroll
        for (int nt = 0; nt < 4; ++nt) {
            #pragma unroll
            for (int ks = 0; ks < 4; ++ks) {
                bhalf8 bf = *(const bhalf8*)&Ks[(nt * 16 + mr) * QS_STRIDE + ks * 32 + q * 8];
                St[nt] = __builtin_amdgcn_mfma_f32_16x16x32_bf16(afr[ks], bf, St[nt], 0, 0, 0);
            }
        }

        float alpha[4];
        #pragma unroll
        for (int r = 0; r < 4; ++r) {
            float mx = fmaxf(fmaxf(St[0][r], St[1][r]), fmaxf(St[2][r], St[3][r]));
            #pragma unroll
            for (int off = 8; off; off >>= 1) mx = fmaxf(mx, __shfl_xor(mx, off));
            float nm = fmaxf(m[r], mx);
            alpha[r] = __expf(m[r] - nm);
            m[r] = nm;
            float ps = 0.f;
            #pragma unroll
            for (int nt = 0; nt < 4; ++nt) {
                float p = __expf(St[nt][r] - nm);
                St[nt][r] = p;
                ps += p;
            }
            #pragma unroll
            for (int off = 8; off; off >>= 1) ps += __shfl_xor(ps, off);
            l[r] = l[r] * alpha[r] + ps;
        }
        #pragma unroll
        for (int nt = 0; nt < 4; ++nt) {
            #pragma unroll
            for (int r = 0; r < 4; ++r) {
                Ps[(w * 16 + q * 4 + r) * PS_STRIDE + nt * 16 + mr] = f2b(St[nt][r]);
                O[nt][r] *= alpha[r];
            }
        }

        #pragma unroll
        for (int ks = 0; ks < 2; ++ks) {
            bhalf8 pa = *(const bhalf8*)&Ps[(w * 16 + mr) * PS_STRIDE + ks * 32 + q * 8];
            #pragma unroll
            for (int nt = 0; nt < 4; ++nt) {
                bhalf8 bf = *(const bhalf8*)&Vt[(nt * 16 + mr) * PS_STRIDE + ks * 32 + q * 8];
                O[nt] = __builtin_amdgcn_mfma_f32_16x16x32_bf16(pa, bf, O[nt], 0, 0, 0);
            }
        }
        __syncthreads();
    }

    #pragma unroll
    for (int nt = 0; nt < 4; ++nt) {
        int d = nt * 16 + mr;
        #pragma unroll
        for (int r = 0; r < 4; ++r) {
            int row = qt * 64 + w * 16 + q * 4 + r;
            out[((size_t)(b * S_ + row)) * D_ + h * 64 + d] = f2b(O[nt][r] / l[r]);
        }
    }
}

// ---------------------------------------------------------------------------
// Workspace (104 MB peak, same as passing rounds; live ranges verified):
//   [  0, 40)  WB: bf16 weights TRANSPOSED [N,K] — live whole launch
//   [ 40, 48)  XN(2-3) -> AT(4-5) -> U2(11-12)
//   [ 48, 56)  Qb(3-aug) -> Hb(7-9)
//   [ 56, 72)  Kb(3-aug)[56,64) + Vb(3-attn)[64,72) -> X2 f32(6-13)
//   [ 72,104)  QA[72,88)+KA[88,104)(3-attn) -> U1(8-12)
// ---------------------------------------------------------------------------
extern "C" void kernel_launch(void* const* d_in, const int* in_sizes, int n_in,
                              void* d_out, int out_size, void* d_ws, size_t ws_size,
                              hipStream_t stream) {
    const float* x      = (const float*)d_in[0];
    const float* wq     = (const float*)d_in[1];
    const float* bq     = (const float*)d_in[2];
    const float* wk     = (const float*)d_in[3];
    const float* bk     = (const float*)d_in[4];
    const float* wv     = (const float*)d_in[5];
    const float* bv     = (const float*)d_in[6];
    const float* wo     = (const float*)d_in[7];
    const float* bo     = (const float*)d_in[8];
    const float* Jattn  = (const float*)d_in[9];
    const float* lamA   = (const float*)d_in[10];
    const float* g_attn = (const float*)d_in[11];
    const float* b_attn = (const float*)d_in[12];
    const float* W1     = (const float*)d_in[13];
    const float* b1     = (const float*)d_in[14];
    const float* J1     = (const float*)d_in[15];
    const float* g1     = (const float*)d_in[17];
    const float* be1    = (const float*)d_in[18];
    const float* W2     = (const float*)d_in[19];
    const float* b2     = (const float*)d_in[20];
    const float* J2     = (const float*)d_in[21];
    const float* g2     = (const float*)d_in[23];
    const float* be2    = (const float*)d_in[24];
    const float* g_ffn  = (const float*)d_in[25];
    const float* b_ffn  = (const float*)d_in[26];
    float* out = (float*)d_out;
    (void)ws_size; (void)in_sizes; (void)n_in; (void)out_size;

    char* wsp = (char*)d_ws;
    const size_t MB = 1u << 20;
    u16* WB = (u16*)(wsp);
    const u16* wqT = WB;
    const u16* wkT = WB + ((size_t)1 << 20);
    const u16* wvT = WB + ((size_t)2 << 20);
    const u16* woT = WB + ((size_t)3 << 20);
    const u16* W1T = WB + ((size_t)4 << 20);
    const u16* J1T = WB + ((size_t)8 << 20);
    const u16* W2T = WB + ((size_t)12 << 20);
    const u16* J2T = WB + ((size_t)16 << 20);
    u16*   XN  = (u16*)(wsp + 40 * MB);
    u16*   AT  = (u16*)(wsp + 40 * MB);
    u16*   U2  = (u16*)(wsp + 40 * MB);
    u16*   Qb  = (u16*)(wsp + 48 * MB);
    u16*   Hb  = (u16*)(wsp + 48 * MB);
    u16*   Kb  = (u16*)(wsp + 56 * MB);
    float* X2  = (float*)(wsp + 56 * MB);
    u16*   Vb  = (u16*)(wsp + 64 * MB);
    u16*   QA  = (u16*)(wsp + 72 * MB);
    u16*   KA  = (u16*)(wsp + 88 * MB);
    u16*   U1  = (u16*)(wsp + 72 * MB);

    dim3 blk(256);
    // 0) weights f32 -> bf16, transposed to [N,K]
    cvt_t_k<<<5120, blk, 0, stream>>>(wq, wk, wv, wo, W1, J1, W2, J2, WB);
    // 1) attention pre-norm
    ln_k<<<NTOK, blk, 0, stream>>>(x, g_attn, b_attn, XN, D_);
    // 2) Q,K,V projections (128x128 tile, global_load_lds)
    gemm128<false, 0><<<dim3(D_ / 128, NTOK / 128), blk, 0, stream>>>(XN, wqT, bq, nullptr, Qb, NTOK, D_, D_);
    gemm128<false, 0><<<dim3(D_ / 128, NTOK / 128), blk, 0, stream>>>(XN, wkT, bk, nullptr, Kb, NTOK, D_, D_);
    gemm128<false, 0><<<dim3(D_ / 128, NTOK / 128), blk, 0, stream>>>(XN, wvT, bv, nullptr, Vb, NTOK, D_, D_);
    // 3) augmented heads
    aug_q_k<<<B_ * H_ * (S_ / 64), blk, 0, stream>>>(Qb, Jattn, lamA, QA);
    aug_k_k<<<(NTOK * D_) / 256, blk, 0, stream>>>(Kb, KA);
    // 4) MFMA flash attention
    attn_k<<<B_ * H_ * (S_ / 64), blk, 0, stream>>>(QA, KA, Vb, AT);
    // 5) output projection + residual -> f32 trunk X2
    gemm128<false, 1><<<dim3(D_ / 128, NTOK / 128), blk, 0, stream>>>(AT, woT, bo, x, X2, NTOK, D_, D_);
    // 6) ffn pre-norm
    ln_k<<<NTOK, blk, 0, stream>>>(X2, g_ffn, b_ffn, Hb, D_);
    // 7) QBNN layer 1: W-pass, then tanh-A J-pass with in-place combine, then LN+GELU
    gemm128<false, 0><<<dim3(FF_ / 128, NTOK / 128), blk, 0, stream>>>(Hb, W1T, b1, nullptr, U1, NTOK, FF_, D_);
    gemm128<true, 2><<<dim3(FF_ / 128, NTOK / 128), blk, 0, stream>>>(Hb, J1T, nullptr, nullptr, U1, NTOK, FF_, D_);
    lngelu_k<false, false><<<NTOK, blk, 0, stream>>>(U1, g1, be1, nullptr, U1, FF_);
    // 8) QBNN layer 2, then LN+GELU + trunk residual -> f32 out
    gemm128<false, 0><<<dim3(D_ / 128, NTOK / 128), blk, 0, stream>>>(U1, W2T, b2, nullptr, U2, NTOK, D_, FF_);
    gemm128<true, 2><<<dim3(D_ / 128, NTOK / 128), blk, 0, stream>>>(U1, J2T, nullptr, nullptr, U2, NTOK, D_, FF_);
    lngelu_k<true, true><<<NTOK, blk, 0, stream>>>(U2, g2, be2, X2, out, D_);
}

// Round 6
// 755.733 us; speedup vs baseline: 4.5826x; 1.3811x over previous
//
#include <hip/hip_runtime.h>
#include <cmath>

typedef unsigned short u16;
typedef unsigned int   u32;
typedef short bhalf8 __attribute__((ext_vector_type(8)));
typedef float fx4    __attribute__((ext_vector_type(4)));

#define B_   4
#define S_   1024
#define D_   1024
#define H_   16
#define HD_  64
#define FF_  4096
#define NTOK (B_*S_)
#define QKVW 3072

__device__ __forceinline__ float b2f(u16 u) {
    u32 x = ((u32)u) << 16;
    return __uint_as_float(x);
}
__device__ __forceinline__ u16 f2b(float f) {
    u32 u = __float_as_uint(f);
    u32 r = (u + 0x7fffu + ((u >> 16) & 1u)) >> 16;
    return (u16)r;
}

// async global->LDS, 16B per lane; LDS dest = wave-uniform base + lane*16
#define GLDS16(g, l) __builtin_amdgcn_global_load_lds( \
    (const __attribute__((address_space(1))) void*)(g), \
    (__attribute__((address_space(3))) void*)(l), 16, 0, 0)

// ---------------------------------------------------------------------------
// Weight convert + transpose: f32 [K,N] -> bf16 [N,K] tiles of 64x64.
// Dst elem offsets: wq 0, wk 1M, wv 2M, wo 3M, W1 4M, J1 8M, W2 12M, J2 16M.
// ---------------------------------------------------------------------------
__global__ __launch_bounds__(256) void cvt_t_k(const float* __restrict__ w0, const float* __restrict__ w1,
                                               const float* __restrict__ w2, const float* __restrict__ w3,
                                               const float* __restrict__ W1p, const float* __restrict__ J1p,
                                               const float* __restrict__ W2p, const float* __restrict__ J2p,
                                               u16* __restrict__ dst) {
    __shared__ u16 L[64][65];
    int bid = blockIdx.x, tid = threadIdx.x;
    const float* src; size_t dbase; int Kd, Nd, tk, tn;
    if (bid < 1024)      { int m = bid >> 8, t = bid & 255;
                           src = m == 0 ? w0 : m == 1 ? w1 : m == 2 ? w2 : w3;
                           dbase = (size_t)m << 20; Kd = 1024; Nd = 1024; tk = t >> 4; tn = t & 15; }
    else if (bid < 2048) { int t = bid - 1024; src = W1p; dbase = (size_t)4  << 20; Kd = 1024; Nd = 4096; tk = t >> 6; tn = t & 63; }
    else if (bid < 3072) { int t = bid - 2048; src = J1p; dbase = (size_t)8  << 20; Kd = 1024; Nd = 4096; tk = t >> 6; tn = t & 63; }
    else if (bid < 4096) { int t = bid - 3072; src = W2p; dbase = (size_t)12 << 20; Kd = 4096; Nd = 1024; tk = t >> 4; tn = t & 15; }
    else                 { int t = bid - 4096; src = J2p; dbase = (size_t)16 << 20; Kd = 4096; Nd = 1024; tk = t >> 4; tn = t & 15; }
    int k0 = tk * 64, n0 = tn * 64;
    int r = tid >> 2, c4 = (tid & 3) * 16;
    #pragma unroll
    for (int p = 0; p < 4; ++p) {
        float4 v = *(const float4*)&src[(size_t)(k0 + r) * Nd + n0 + c4 + p * 4];
        L[r][c4 + p * 4 + 0] = f2b(v.x);
        L[r][c4 + p * 4 + 1] = f2b(v.y);
        L[r][c4 + p * 4 + 2] = f2b(v.z);
        L[r][c4 + p * 4 + 3] = f2b(v.w);
    }
    __syncthreads();
    u16 o[16];
    #pragma unroll
    for (int j = 0; j < 16; ++j) o[j] = L[c4 + j][r];
    *(uint4*)&dst[dbase + (size_t)(n0 + r) * Kd + k0 + c4]     = *(uint4*)&o[0];
    *(uint4*)&dst[dbase + (size_t)(n0 + r) * Kd + k0 + c4 + 8] = *(uint4*)&o[8];
}

// elementwise in-place tanh over bf16 buffer, 8 elems/thread
__global__ __launch_bounds__(256) void tanh_k(u16* __restrict__ buf) {
    size_t idx = ((size_t)blockIdx.x * 256 + threadIdx.x) * 8;
    uint4 v = *(uint4*)&buf[idx];
    const u16* p = (const u16*)&v;
    u16 o[8];
    #pragma unroll
    for (int j = 0; j < 8; ++j) o[j] = f2b(tanhf(b2f(p[j])));
    *(uint4*)&buf[idx] = *(uint4*)o;
}

// ---------------------------------------------------------------------------
// 128x128 MFMA GEMM (m97 structure): C[M,N] = A[M,K] @ Bt[N,K]^T + bias
//   EPI 0: store bf16(acc+bias)
//   EPI 1: store f32(acc+bias+resid)        (x + attn@wo)
//   EPI 2: ht=Cout[idx]; Cout=bf16(ht+0.5*acc*tanh(ht))   (QBNN combine)
//   SEG: bias segmented per 1024 cols (fused QKV): b0/b1/b2
// 4 waves in 2x2; each wave 64x64 via 4x4 of 16x16x32 MFMA. BK=32.
// ---------------------------------------------------------------------------
template <int EPI, bool SEG>
__global__ __launch_bounds__(256, 2) void gemm128(const u16* __restrict__ A,
                                                  const u16* __restrict__ Bt,
                                                  const float* __restrict__ bA,
                                                  const float* __restrict__ bB,
                                                  const float* __restrict__ bC,
                                                  const float* __restrict__ resid,
                                                  void* __restrict__ Cout,
                                                  int M, int N, int K) {
    __shared__ u16 As[128 * 32];
    __shared__ u16 Bs[128 * 32];
    const int tid = threadIdx.x;
    const int w = tid >> 6, ln = tid & 63;
    const int q = ln >> 4, mr = ln & 15;
    const int m0 = blockIdx.y * 128, n0 = blockIdx.x * 128;
    const int wm = (w >> 1) * 64, wn = (w & 1) * 64;
    const int sr = w * 16 + (ln >> 2);
    const int sc = (ln & 3) * 8;

    fx4 acc[4][4];
    #pragma unroll
    for (int i = 0; i < 4; ++i)
        #pragma unroll
        for (int j = 0; j < 4; ++j) acc[i][j] = (fx4){0.f, 0.f, 0.f, 0.f};

    const u16* Ab0 = A  + (size_t)(m0 + sr) * K + sc;
    const u16* Ab1 = A  + (size_t)(m0 + sr + 64) * K + sc;
    const u16* Bb0 = Bt + (size_t)(n0 + sr) * K + sc;
    const u16* Bb1 = Bt + (size_t)(n0 + sr + 64) * K + sc;

    for (int k0 = 0; k0 < K; k0 += 32) {
        __syncthreads();
        GLDS16(Ab0 + k0, &As[w * 512]);
        GLDS16(Ab1 + k0, &As[(w + 4) * 512]);
        GLDS16(Bb0 + k0, &Bs[w * 512]);
        GLDS16(Bb1 + k0, &Bs[(w + 4) * 512]);
        __syncthreads();

        bhalf8 af[4], bf[4];
        #pragma unroll
        for (int i = 0; i < 4; ++i) af[i] = *(const bhalf8*)&As[(wm + i * 16 + mr) * 32 + q * 8];
        #pragma unroll
        for (int j = 0; j < 4; ++j) bf[j] = *(const bhalf8*)&Bs[(wn + j * 16 + mr) * 32 + q * 8];
        #pragma unroll
        for (int i = 0; i < 4; ++i)
            #pragma unroll
            for (int j = 0; j < 4; ++j)
                acc[i][j] = __builtin_amdgcn_mfma_f32_16x16x32_bf16(af[i], bf[j], acc[i][j], 0, 0, 0);
    }

    #pragma unroll
    for (int j = 0; j < 4; ++j) {
        int col = n0 + wn + j * 16 + mr;
        float bs;
        if (SEG) {
            const float* bp = col < 1024 ? bA : (col < 2048 ? bB : bC);
            bs = bp[col & 1023];
        } else {
            bs = bA ? bA[col] : 0.f;
        }
        #pragma unroll
        for (int i = 0; i < 4; ++i) {
            #pragma unroll
            for (int r = 0; r < 4; ++r) {
                int row    = m0 + wm + i * 16 + q * 4 + r;
                size_t idx = (size_t)row * N + col;
                float v    = acc[i][j][r] + bs;
                if (EPI == 0) {
                    ((u16*)Cout)[idx] = f2b(v);
                } else if (EPI == 1) {
                    ((float*)Cout)[idx] = v + resid[idx];
                } else {
                    float ht = b2f(((u16*)Cout)[idx]);
                    ((u16*)Cout)[idx] = f2b(ht + 0.5f * v * tanhf(ht));
                }
            }
        }
    }
}

// ---------------------------------------------------------------------------
// LayerNorm over f32 input rows -> bf16 out.
// ---------------------------------------------------------------------------
__global__ __launch_bounds__(256) void ln_k(const float* __restrict__ xin,
                                            const float* __restrict__ g,
                                            const float* __restrict__ bb,
                                            u16* __restrict__ out, int W) {
    __shared__ float red[8], red2[8], stats[2];
    int row = blockIdx.x, tid = threadIdx.x;
    float s = 0.f, ss = 0.f;
    for (int c = tid; c < W; c += 256) {
        float v = xin[(size_t)row * W + c];
        s += v; ss += v * v;
    }
    #pragma unroll
    for (int off = 32; off; off >>= 1) { s += __shfl_xor(s, off); ss += __shfl_xor(ss, off); }
    int wave = tid >> 6, lane = tid & 63;
    if (lane == 0) { red[wave] = s; red2[wave] = ss; }
    __syncthreads();
    if (tid == 0) {
        float S = 0.f, SS = 0.f;
        for (int w2 = 0; w2 < 4; ++w2) { S += red[w2]; SS += red2[w2]; }
        float mu = S / W;
        stats[0] = mu;
        stats[1] = rsqrtf(SS / W - mu * mu + 1e-5f);
    }
    __syncthreads();
    float mu = stats[0], rs = stats[1];
    for (int c = tid; c < W; c += 256)
        out[(size_t)row * W + c] = f2b((xin[(size_t)row * W + c] - mu) * rs * g[c] + bb[c]);
}

// ---------------------------------------------------------------------------
// LN + exact GELU over bf16 rows u. RES: add f32 resid. OUT_F32: f32 out.
// In-place safe: all u reads precede the barrier before writes.
// ---------------------------------------------------------------------------
template <bool RES, bool OUT_F32>
__global__ __launch_bounds__(256) void lngelu_k(const u16* __restrict__ u,
                                                const float* __restrict__ g,
                                                const float* __restrict__ be,
                                                const float* __restrict__ resid,
                                                void* __restrict__ out, int W) {
    __shared__ float ub[4096];
    __shared__ float red[8], red2[8], stats[2];
    int row = blockIdx.x, tid = threadIdx.x;
    float s = 0.f, ss = 0.f;
    for (int c = tid; c < W; c += 256) {
        float v = b2f(u[(size_t)row * W + c]);
        ub[c] = v; s += v; ss += v * v;
    }
    #pragma unroll
    for (int off = 32; off; off >>= 1) { s += __shfl_xor(s, off); ss += __shfl_xor(ss, off); }
    int wave = tid >> 6, lane = tid & 63;
    if (lane == 0) { red[wave] = s; red2[wave] = ss; }
    __syncthreads();
    if (tid == 0) {
        float S = 0.f, SS = 0.f;
        for (int w2 = 0; w2 < 4; ++w2) { S += red[w2]; SS += red2[w2]; }
        float mu = S / W;
        stats[0] = mu;
        stats[1] = rsqrtf(SS / W - mu * mu + 1e-5f);
    }
    __syncthreads();
    float mu = stats[0], rs = stats[1];
    for (int c = tid; c < W; c += 256) {
        float v = (ub[c] - mu) * rs * g[c] + be[c];
        float y = 0.5f * v * (1.f + erff(v * 0.70710678118654752f));
        if (RES) y += resid[(size_t)row * W + c];
        if (OUT_F32) ((float*)out)[(size_t)row * W + c] = y;
        else         ((u16*)out)[(size_t)row * W + c] = f2b(y);
    }
}

// ---------------------------------------------------------------------------
// Qaug[B,H,S,128]: [0:64]=Q/8, [64:128]=lam*(tanh(Q)@J[h]).
// Q lives in fused QKV buffer [NTOK, 3072], cols [0,1024).
// ---------------------------------------------------------------------------
__global__ __launch_bounds__(256) void aug_q_k(const u16* __restrict__ QKV,
                                               const float* __restrict__ J,
                                               const float* __restrict__ lamp,
                                               u16* __restrict__ QA) {
    __shared__ float Jl[64][65];
    __shared__ float Tq[64][65];
    int blk = blockIdx.x;
    int bh = blk >> 4, st = blk & 15;
    int b = bh >> 4, h = bh & 15;
    int s0 = st * 64;
    int tid = threadIdx.x;
    float lam = lamp[0];

    for (int i = tid; i < 4096; i += 256)
        Jl[i >> 6][i & 63] = J[h * 4096 + i];
    for (int i = tid; i < 4096; i += 256) {
        int r = i >> 6, c = i & 63;
        float v  = b2f(QKV[(size_t)(b * S_ + s0 + r) * QKVW + h * 64 + c]);
        Tq[r][c] = tanhf(v);
        QA[((size_t)(bh * S_ + s0 + r)) * 128 + c] = f2b(v * 0.125f);  // /sqrt(64)
    }
    __syncthreads();

    int r = tid >> 2, c0 = (tid & 3) * 16;
    float acc[16];
    #pragma unroll
    for (int j = 0; j < 16; ++j) acc[j] = 0.f;
    for (int k = 0; k < 64; ++k) {
        float a = Tq[r][k];
        #pragma unroll
        for (int j = 0; j < 16; ++j) acc[j] += a * Jl[k][c0 + j];
    }
    size_t orow = ((size_t)(bh * S_ + s0 + r)) * 128 + 64 + c0;
    #pragma unroll
    for (int j = 0; j < 16; ++j) QA[orow + j] = f2b(lam * acc[j]);
}

// Kaug[B,H,S,128]: [0:64]=K, [64:128]=tanh(K). K in QKV cols [1024,2048).
__global__ __launch_bounds__(256) void aug_k_k(const u16* __restrict__ QKV,
                                               u16* __restrict__ KA) {
    int idx = blockIdx.x * 256 + threadIdx.x;  // < B*S*D
    int d = idx & (D_ - 1);
    int bs = idx >> 10;
    int h = d >> 6, hd = d & 63;
    int b = bs >> 10, si = bs & (S_ - 1);
    u16 v      = QKV[(size_t)bs * QKVW + 1024 + d];
    size_t row = (size_t)((b * H_ + h) * S_ + si);
    KA[row * 128 + hd]      = v;
    KA[row * 128 + 64 + hd] = f2b(tanhf(b2f(v)));
}

// ---------------------------------------------------------------------------
// MFMA flash attention. V in QKV cols [2048,3072).
// ---------------------------------------------------------------------------
#define QS_STRIDE 136
#define PS_STRIDE 72
__global__ __launch_bounds__(256) void attn_k(const u16* __restrict__ QA,
                                              const u16* __restrict__ KA,
                                              const u16* __restrict__ QKV,
                                              u16* __restrict__ out) {
    __shared__ u16 Qs[64 * QS_STRIDE];
    __shared__ u16 Ks[64 * QS_STRIDE];
    __shared__ u16 Vt[64 * PS_STRIDE];
    __shared__ u16 Ps[4 * 16 * PS_STRIDE];

    const int tid  = threadIdx.x;
    const int w    = tid >> 6, lane = tid & 63;
    const int q    = lane >> 4, mr = lane & 15;
    const int bh   = blockIdx.x >> 4;
    const int qt   = blockIdx.x & 15;
    const int b    = bh >> 4, h = bh & 15;

    #pragma unroll
    for (int p = 0; p < 4; ++p) {
        int idx = p * 2048 + tid * 8;
        int row = idx >> 7, col = idx & 127;
        uint4 v4 = *(const uint4*)&QA[((size_t)(bh * S_ + qt * 64 + row)) * 128 + col];
        *(uint4*)&Qs[row * QS_STRIDE + col] = v4;
    }

    fx4 zero = {0.f, 0.f, 0.f, 0.f};
    fx4 O[4] = {zero, zero, zero, zero};
    float m[4]  = {-3e38f, -3e38f, -3e38f, -3e38f};
    float l[4]  = {0.f, 0.f, 0.f, 0.f};

    for (int kt = 0; kt < 16; ++kt) {
        #pragma unroll
        for (int p = 0; p < 4; ++p) {
            int idx = p * 2048 + tid * 8;
            int row = idx >> 7, col = idx & 127;
            uint4 v4 = *(const uint4*)&KA[((size_t)(bh * S_ + kt * 64 + row)) * 128 + col];
            *(uint4*)&Ks[row * QS_STRIDE + col] = v4;
        }
        #pragma unroll
        for (int p = 0; p < 2; ++p) {
            int idx = p * 2048 + tid * 8;
            int key = idx >> 6, d0 = idx & 63;
            uint4 v4 = *(const uint4*)&QKV[((size_t)(b * S_ + kt * 64 + key)) * QKVW + 2048 + h * 64 + d0];
            const u16* vp = (const u16*)&v4;
            #pragma unroll
            for (int j = 0; j < 8; ++j) Vt[(d0 + j) * PS_STRIDE + key] = vp[j];
        }
        __syncthreads();

        fx4 St[4] = {zero, zero, zero, zero};
        bhalf8 afr[4];
        #pragma unroll
        for (int ks = 0; ks < 4; ++ks)
            afr[ks] = *(const bhalf8*)&Qs[(w * 16 + mr) * QS_STRIDE + ks * 32 + q * 8];
        #pragma unroll
        for (int nt = 0; nt < 4; ++nt) {
            #pragma unroll
            for (int ks = 0; ks < 4; ++ks) {
                bhalf8 bf = *(const bhalf8*)&Ks[(nt * 16 + mr) * QS_STRIDE + ks * 32 + q * 8];
                St[nt] = __builtin_amdgcn_mfma_f32_16x16x32_bf16(afr[ks], bf, St[nt], 0, 0, 0);
            }
        }

        float alpha[4];
        #pragma unroll
        for (int r = 0; r < 4; ++r) {
            float mx = fmaxf(fmaxf(St[0][r], St[1][r]), fmaxf(St[2][r], St[3][r]));
            #pragma unroll
            for (int off = 8; off; off >>= 1) mx = fmaxf(mx, __shfl_xor(mx, off));
            float nm = fmaxf(m[r], mx);
            alpha[r] = __expf(m[r] - nm);
            m[r] = nm;
            float ps = 0.f;
            #pragma unroll
            for (int nt = 0; nt < 4; ++nt) {
                float p = __expf(St[nt][r] - nm);
                St[nt][r] = p;
                ps += p;
            }
            #pragma unroll
            for (int off = 8; off; off >>= 1) ps += __shfl_xor(ps, off);
            l[r] = l[r] * alpha[r] + ps;
        }
        #pragma unroll
        for (int nt = 0; nt < 4; ++nt) {
            #pragma unroll
            for (int r = 0; r < 4; ++r) {
                Ps[(w * 16 + q * 4 + r) * PS_STRIDE + nt * 16 + mr] = f2b(St[nt][r]);
                O[nt][r] *= alpha[r];
            }
        }

        #pragma unroll
        for (int ks = 0; ks < 2; ++ks) {
            bhalf8 pa = *(const bhalf8*)&Ps[(w * 16 + mr) * PS_STRIDE + ks * 32 + q * 8];
            #pragma unroll
            for (int nt = 0; nt < 4; ++nt) {
                bhalf8 bf = *(const bhalf8*)&Vt[(nt * 16 + mr) * PS_STRIDE + ks * 32 + q * 8];
                O[nt] = __builtin_amdgcn_mfma_f32_16x16x32_bf16(pa, bf, O[nt], 0, 0, 0);
            }
        }
        __syncthreads();
    }

    #pragma unroll
    for (int nt = 0; nt < 4; ++nt) {
        int d = nt * 16 + mr;
        #pragma unroll
        for (int r = 0; r < 4; ++r) {
            int row = qt * 64 + w * 16 + q * 4 + r;
            out[((size_t)(b * S_ + row)) * D_ + h * 64 + d] = f2b(O[nt][r] / l[r]);
        }
    }
}

// ---------------------------------------------------------------------------
// Workspace (104 MB peak; live ranges verified):
//   [  0, 40)  WB: bf16 weights TRANSPOSED [N,K] — live whole launch
//   [ 40, 48)  XN(1-2) -> AT(4-5) -> U2(8-9)
//   [ 48, 72)  QKV fused [NTOK,3072] (2-4) -> Hb[48,56)(6-7) + X2 f32[56,72)(5-9)
//   [ 72,104)  QA[72,88)+KA[88,104)(3-4) -> U1(7-9)
// ---------------------------------------------------------------------------
extern "C" void kernel_launch(void* const* d_in, const int* in_sizes, int n_in,
                              void* d_out, int out_size, void* d_ws, size_t ws_size,
                              hipStream_t stream) {
    const float* x      = (const float*)d_in[0];
    const float* wq     = (const float*)d_in[1];
    const float* bq     = (const float*)d_in[2];
    const float* wk     = (const float*)d_in[3];
    const float* bk     = (const float*)d_in[4];
    const float* wv     = (const float*)d_in[5];
    const float* bv     = (const float*)d_in[6];
    const float* wo     = (const float*)d_in[7];
    const float* bo     = (const float*)d_in[8];
    const float* Jattn  = (const float*)d_in[9];
    const float* lamA   = (const float*)d_in[10];
    const float* g_attn = (const float*)d_in[11];
    const float* b_attn = (const float*)d_in[12];
    const float* W1     = (const float*)d_in[13];
    const float* b1     = (const float*)d_in[14];
    const float* J1     = (const float*)d_in[15];
    const float* g1     = (const float*)d_in[17];
    const float* be1    = (const float*)d_in[18];
    const float* W2     = (const float*)d_in[19];
    const float* b2     = (const float*)d_in[20];
    const float* J2     = (const float*)d_in[21];
    const float* g2     = (const float*)d_in[23];
    const float* be2    = (const float*)d_in[24];
    const float* g_ffn  = (const float*)d_in[25];
    const float* b_ffn  = (const float*)d_in[26];
    float* out = (float*)d_out;
    (void)ws_size; (void)in_sizes; (void)n_in; (void)out_size;

    char* wsp = (char*)d_ws;
    const size_t MB = 1u << 20;
    u16* WB = (u16*)(wsp);
    const u16* qkvT = WB;                        // wq|wk|wv transposed, [3072,1024]
    const u16* woT  = WB + ((size_t)3 << 20);
    const u16* W1T  = WB + ((size_t)4 << 20);
    const u16* J1T  = WB + ((size_t)8 << 20);
    const u16* W2T  = WB + ((size_t)12 << 20);
    const u16* J2T  = WB + ((size_t)16 << 20);
    u16*   XN   = (u16*)(wsp + 40 * MB);
    u16*   AT   = (u16*)(wsp + 40 * MB);
    u16*   U2   = (u16*)(wsp + 40 * MB);
    u16*   QKVb = (u16*)(wsp + 48 * MB);
    u16*   Hb   = (u16*)(wsp + 48 * MB);
    float* X2   = (float*)(wsp + 56 * MB);
    u16*   QA   = (u16*)(wsp + 72 * MB);
    u16*   KA   = (u16*)(wsp + 88 * MB);
    u16*   U1   = (u16*)(wsp + 72 * MB);

    dim3 blk(256);
    // 0) weights f32 -> bf16, transposed to [N,K]
    cvt_t_k<<<5120, blk, 0, stream>>>(wq, wk, wv, wo, W1, J1, W2, J2, WB);
    // 1) attention pre-norm
    ln_k<<<NTOK, blk, 0, stream>>>(x, g_attn, b_attn, XN, D_);
    // 2) fused QKV projection: [NTOK,3072]
    gemm128<0, true><<<dim3(QKVW / 128, NTOK / 128), blk, 0, stream>>>(XN, qkvT, bq, bk, bv, nullptr, QKVb, NTOK, QKVW, D_);
    // 3) augmented heads
    aug_q_k<<<B_ * H_ * (S_ / 64), blk, 0, stream>>>(QKVb, Jattn, lamA, QA);
    aug_k_k<<<(NTOK * D_) / 256, blk, 0, stream>>>(QKVb, KA);
    // 4) MFMA flash attention
    attn_k<<<B_ * H_ * (S_ / 64), blk, 0, stream>>>(QA, KA, QKVb, AT);
    // 5) output projection + residual -> f32 trunk X2
    gemm128<1, false><<<dim3(D_ / 128, NTOK / 128), blk, 0, stream>>>(AT, woT, bo, nullptr, nullptr, x, X2, NTOK, D_, D_);
    // 6) ffn pre-norm
    ln_k<<<NTOK, blk, 0, stream>>>(X2, g_ffn, b_ffn, Hb, D_);
    // 7) QBNN layer 1: W-pass -> U1; tanh(Hb) in place; J-pass combine; LN+GELU
    gemm128<0, false><<<dim3(FF_ / 128, NTOK / 128), blk, 0, stream>>>(Hb, W1T, b1, nullptr, nullptr, nullptr, U1, NTOK, FF_, D_);
    tanh_k<<<(NTOK * D_) / 2048, blk, 0, stream>>>(Hb);
    gemm128<2, false><<<dim3(FF_ / 128, NTOK / 128), blk, 0, stream>>>(Hb, J1T, nullptr, nullptr, nullptr, nullptr, U1, NTOK, FF_, D_);
    lngelu_k<false, false><<<NTOK, blk, 0, stream>>>(U1, g1, be1, nullptr, U1, FF_);
    // 8) QBNN layer 2: W-pass -> U2; tanh(U1) in place; J-pass combine; LN+GELU+resid
    gemm128<0, false><<<dim3(D_ / 128, NTOK / 128), blk, 0, stream>>>(U1, W2T, b2, nullptr, nullptr, nullptr, U2, NTOK, D_, FF_);
    tanh_k<<<(NTOK * FF_) / 2048, blk, 0, stream>>>(U1);
    gemm128<2, false><<<dim3(D_ / 128, NTOK / 128), blk, 0, stream>>>(U1, J2T, nullptr, nullptr, nullptr, nullptr, U2, NTOK, D_, FF_);
    lngelu_k<true, true><<<NTOK, blk, 0, stream>>>(U2, g2, be2, X2, out, D_);
}